// Round 1
// baseline (2339.725 us; speedup 1.0000x reference)
//
#include <hip/hip_runtime.h>
#include <math.h>

#define BB 2
#define SS 2048
#define DD 1024
#define HH 16
#define HDIM 64

// ---------------------------------------------------------------------------
// GEMM: Y = X @ W^T + bias.  X[M,K] row-major, W[N,K] row-major (torch Linear).
// LAYOUT 0: Y[m*N + n]                     (plain [M,N])
// LAYOUT 1: Y[((b*H + h)*S + s)*HD + hd]   (split heads: m=b*S+s, n=h*HD+hd)
// 64x64 tile, BK=16, 256 threads, 4x4 microtile.
// ---------------------------------------------------------------------------
template <int LAYOUT>
__global__ __launch_bounds__(256) void gemm_bias_kernel(
    const float* __restrict__ X, const float* __restrict__ W,
    const float* __restrict__ bias, float* __restrict__ Y,
    int M, int N, int K)
{
    __shared__ float Xs[64][17];
    __shared__ float Ws[64][17];

    const int tid = threadIdx.x;
    const int tx = tid & 15;
    const int ty = tid >> 4;
    const int m0 = blockIdx.y << 6;
    const int n0 = blockIdx.x << 6;
    const int lrow = tid >> 2;
    const int lcol = (tid & 3) << 2;

    float acc[4][4] = {};

    for (int k0 = 0; k0 < K; k0 += 16) {
        const float4 xv = *reinterpret_cast<const float4*>(
            &X[(size_t)(m0 + lrow) * K + k0 + lcol]);
        const float4 wv = *reinterpret_cast<const float4*>(
            &W[(size_t)(n0 + lrow) * K + k0 + lcol]);
        Xs[lrow][lcol + 0] = xv.x; Xs[lrow][lcol + 1] = xv.y;
        Xs[lrow][lcol + 2] = xv.z; Xs[lrow][lcol + 3] = xv.w;
        Ws[lrow][lcol + 0] = wv.x; Ws[lrow][lcol + 1] = wv.y;
        Ws[lrow][lcol + 2] = wv.z; Ws[lrow][lcol + 3] = wv.w;
        __syncthreads();

        #pragma unroll
        for (int kk = 0; kk < 16; ++kk) {
            float a[4], b[4];
            #pragma unroll
            for (int i = 0; i < 4; ++i) a[i] = Xs[ty + (i << 4)][kk];
            #pragma unroll
            for (int j = 0; j < 4; ++j) b[j] = Ws[tx + (j << 4)][kk];
            #pragma unroll
            for (int i = 0; i < 4; ++i)
                #pragma unroll
                for (int j = 0; j < 4; ++j)
                    acc[i][j] = fmaf(a[i], b[j], acc[i][j]);
        }
        __syncthreads();
    }

    #pragma unroll
    for (int i = 0; i < 4; ++i) {
        const int m = m0 + ty + (i << 4);
        #pragma unroll
        for (int j = 0; j < 4; ++j) {
            const int n = n0 + tx + (j << 4);
            const float v = acc[i][j] + bias[n];
            if (LAYOUT == 0) {
                Y[(size_t)m * N + n] = v;
            } else {
                const int b_ = m >> 11;          // m / S
                const int s_ = m & (SS - 1);
                const int h_ = n >> 6;           // n / HD
                const int d_ = n & (HDIM - 1);
                Y[(((size_t)(b_ * HH + h_)) * SS + s_) * HDIM + d_] = v;
            }
        }
    }
}

// ---------------------------------------------------------------------------
// Flash-style attention, fp32.
// Grid: (S/32, B*H). Block: 256 threads.
// Each block: 32 query rows of one (b,h). Loop over 64-key tiles in LDS.
// Thread t: q row = t/8; owns k-slice and d-slice [ (t%8)*8 .. +8 ).
// Online softmax state per thread (m shared across the 8 lanes of a row via
// shuffle; l and O accumulated per-thread, combined at the end).
// ---------------------------------------------------------------------------
__global__ __launch_bounds__(256) void attn_kernel(
    const float* __restrict__ Qp, const float* __restrict__ Kp,
    const float* __restrict__ Vp, const int* __restrict__ mask,
    float* __restrict__ AO)
{
    __shared__ float Qs[32][65];
    __shared__ float Ks[64][65];
    __shared__ float Vs[64][65];
    __shared__ float Ps[32][65];

    const int tid = threadIdx.x;
    const int bh  = blockIdx.y;
    const int b_  = bh >> 4;
    const int h_  = bh & (HH - 1);
    const int q0  = blockIdx.x << 5;

    const float* Qb = Qp + (size_t)bh * SS * HDIM;
    const float* Kb = Kp + (size_t)bh * SS * HDIM;
    const float* Vb = Vp + (size_t)bh * SS * HDIM;

    // Load the 32x64 Q tile (8 floats per thread).
    {
        const int r = tid >> 3;
        const int c = (tid & 7) << 3;
        const float4 a0 = *reinterpret_cast<const float4*>(
            &Qb[(size_t)(q0 + r) * HDIM + c]);
        const float4 a1 = *reinterpret_cast<const float4*>(
            &Qb[(size_t)(q0 + r) * HDIM + c + 4]);
        Qs[r][c + 0] = a0.x; Qs[r][c + 1] = a0.y;
        Qs[r][c + 2] = a0.z; Qs[r][c + 3] = a0.w;
        Qs[r][c + 4] = a1.x; Qs[r][c + 5] = a1.y;
        Qs[r][c + 6] = a1.z; Qs[r][c + 7] = a1.w;
    }

    const int ql  = tid >> 3;       // 0..31  query row within tile
    const int kb  = (tid & 7) << 3; // 0..56  k-slice / d-slice base

    float m_run  = -INFINITY;
    float l_part = 0.0f;
    float o_acc[8] = {0.f, 0.f, 0.f, 0.f, 0.f, 0.f, 0.f, 0.f};

    const int* mrow = mask + ((size_t)b_ * SS + (size_t)(q0 + ql)) * SS;

    for (int kt = 0; kt < SS; kt += 64) {
        // Load K and V 64x64 tiles (16 floats of each per thread).
        {
            const int r = tid >> 2;
            const int c = (tid & 3) << 4;
            const float* ksrc = &Kb[(size_t)(kt + r) * HDIM + c];
            const float* vsrc = &Vb[(size_t)(kt + r) * HDIM + c];
            #pragma unroll
            for (int u = 0; u < 4; ++u) {
                const float4 kv = *reinterpret_cast<const float4*>(ksrc + 4 * u);
                const float4 vv = *reinterpret_cast<const float4*>(vsrc + 4 * u);
                Ks[r][c + 4 * u + 0] = kv.x; Ks[r][c + 4 * u + 1] = kv.y;
                Ks[r][c + 4 * u + 2] = kv.z; Ks[r][c + 4 * u + 3] = kv.w;
                Vs[r][c + 4 * u + 0] = vv.x; Vs[r][c + 4 * u + 1] = vv.y;
                Vs[r][c + 4 * u + 2] = vv.z; Vs[r][c + 4 * u + 3] = vv.w;
            }
        }
        __syncthreads();

        // Scores: 8 keys per thread, dot over HD=64.
        float s[8] = {0.f, 0.f, 0.f, 0.f, 0.f, 0.f, 0.f, 0.f};
        #pragma unroll 16
        for (int dd = 0; dd < HDIM; ++dd) {
            const float qv = Qs[ql][dd];
            #pragma unroll
            for (int j = 0; j < 8; ++j)
                s[j] = fmaf(qv, Ks[kb + j][dd], s[j]);
        }

        const int4 mm0 = *reinterpret_cast<const int4*>(&mrow[kt + kb]);
        const int4 mm1 = *reinterpret_cast<const int4*>(&mrow[kt + kb + 4]);
        const int mv[8] = {mm0.x, mm0.y, mm0.z, mm0.w,
                           mm1.x, mm1.y, mm1.z, mm1.w};
        #pragma unroll
        for (int j = 0; j < 8; ++j) {
            s[j] *= 0.125f;                 // 1/sqrt(HD) = 1/8
            if (mv[j] == 0) s[j] = -1e9f;
        }

        // Row max across this thread's 8 keys, then across the row's 8 lanes.
        float tm = s[0];
        #pragma unroll
        for (int j = 1; j < 8; ++j) tm = fmaxf(tm, s[j]);
        tm = fmaxf(tm, __shfl_xor(tm, 1));
        tm = fmaxf(tm, __shfl_xor(tm, 2));
        tm = fmaxf(tm, __shfl_xor(tm, 4));

        const float m_new = fmaxf(m_run, tm);
        const float corr  = __expf(m_run - m_new);   // first iter: exp(-inf)=0
        l_part *= corr;
        #pragma unroll
        for (int d2 = 0; d2 < 8; ++d2) o_acc[d2] *= corr;

        float psum = 0.f;
        #pragma unroll
        for (int j = 0; j < 8; ++j) {
            const float p = __expf(s[j] - m_new);
            psum += p;
            Ps[ql][kb + j] = p;
        }
        l_part += psum;
        m_run = m_new;
        __syncthreads();

        // O += P * V  (each thread: all 64 keys for its 8 output dims)
        #pragma unroll 8
        for (int kk2 = 0; kk2 < 64; ++kk2) {
            const float p = Ps[ql][kk2];
            #pragma unroll
            for (int d2 = 0; d2 < 8; ++d2)
                o_acc[d2] = fmaf(p, Vs[kk2][kb + d2], o_acc[d2]);
        }
        __syncthreads();
    }

    float lsum = l_part;
    lsum += __shfl_xor(lsum, 1);
    lsum += __shfl_xor(lsum, 2);
    lsum += __shfl_xor(lsum, 4);
    const float invl = 1.0f / lsum;

    const float4 o0 = make_float4(o_acc[0] * invl, o_acc[1] * invl,
                                  o_acc[2] * invl, o_acc[3] * invl);
    const float4 o1 = make_float4(o_acc[4] * invl, o_acc[5] * invl,
                                  o_acc[6] * invl, o_acc[7] * invl);
    // AO layout: [B, S, D]  (heads re-merged: d = h*HD + hd)
    float* dst = &AO[((size_t)b_ * SS + (size_t)(q0 + ql)) * DD + h_ * HDIM + kb];
    *reinterpret_cast<float4*>(dst)     = o0;
    *reinterpret_cast<float4*>(dst + 4) = o1;
}

// ---------------------------------------------------------------------------
extern "C" void kernel_launch(void* const* d_in, const int* in_sizes, int n_in,
                              void* d_out, int out_size, void* d_ws, size_t ws_size,
                              hipStream_t stream)
{
    const float* q    = (const float*)d_in[0];
    const float* k    = (const float*)d_in[1];
    const float* v    = (const float*)d_in[2];
    const int*   mask = (const int*)d_in[3];
    const float* Wq   = (const float*)d_in[4];
    const float* bq   = (const float*)d_in[5];
    const float* Wk   = (const float*)d_in[6];
    const float* bk   = (const float*)d_in[7];
    const float* Wv   = (const float*)d_in[8];
    const float* bv   = (const float*)d_in[9];
    const float* Wo   = (const float*)d_in[10];
    const float* bo   = (const float*)d_in[11];
    float* out = (float*)d_out;

    const size_t per = (size_t)BB * HH * SS * HDIM;  // 4,194,304 floats
    float* Qp = (float*)d_ws;
    float* Kp = Qp + per;
    float* Vp = Kp + per;
    float* AO = Vp + per;                            // [B,S,D]

    const dim3 gblk(DD / 64, (BB * SS) / 64);        // (16, 64)
    gemm_bias_kernel<1><<<gblk, 256, 0, stream>>>(q, Wq, bq, Qp, BB * SS, DD, DD);
    gemm_bias_kernel<1><<<gblk, 256, 0, stream>>>(k, Wk, bk, Kp, BB * SS, DD, DD);
    gemm_bias_kernel<1><<<gblk, 256, 0, stream>>>(v, Wv, bv, Vp, BB * SS, DD, DD);

    const dim3 gattn(SS / 32, BB * HH);              // (64, 32)
    attn_kernel<<<gattn, 256, 0, stream>>>(Qp, Kp, Vp, mask, AO);

    gemm_bias_kernel<0><<<gblk, 256, 0, stream>>>(AO, Wo, bo, out, BB * SS, DD, DD);
}

// Round 2
// 756.008 us; speedup vs baseline: 3.0948x; 3.0948x over previous
//
#include <hip/hip_runtime.h>
#include <math.h>

#define BB 2
#define SS 2048
#define DD 1024
#define HH 16
#define HDIM 64

typedef _Float16 f16x4 __attribute__((ext_vector_type(4)));
typedef _Float16 f16x8 __attribute__((ext_vector_type(8)));
typedef float    f32x4 __attribute__((ext_vector_type(4)));

// ---------------------------------------------------------------------------
// GEMM: Y = X @ W^T + bias (fp32 compute).  X[M,K], W[N,K] row-major.
// Plain fp32 [M,N] output (final projection).
// ---------------------------------------------------------------------------
__global__ __launch_bounds__(256) void gemm_bias_f32(
    const float* __restrict__ X, const float* __restrict__ W,
    const float* __restrict__ bias, float* __restrict__ Y,
    int M, int N, int K)
{
    __shared__ float Xs[64][17];
    __shared__ float Ws[64][17];

    const int tid = threadIdx.x;
    const int tx = tid & 15;
    const int ty = tid >> 4;
    const int m0 = blockIdx.y << 6;
    const int n0 = blockIdx.x << 6;
    const int lrow = tid >> 2;
    const int lcol = (tid & 3) << 2;

    float acc[4][4] = {};

    for (int k0 = 0; k0 < K; k0 += 16) {
        const float4 xv = *reinterpret_cast<const float4*>(
            &X[(size_t)(m0 + lrow) * K + k0 + lcol]);
        const float4 wv = *reinterpret_cast<const float4*>(
            &W[(size_t)(n0 + lrow) * K + k0 + lcol]);
        Xs[lrow][lcol + 0] = xv.x; Xs[lrow][lcol + 1] = xv.y;
        Xs[lrow][lcol + 2] = xv.z; Xs[lrow][lcol + 3] = xv.w;
        Ws[lrow][lcol + 0] = wv.x; Ws[lrow][lcol + 1] = wv.y;
        Ws[lrow][lcol + 2] = wv.z; Ws[lrow][lcol + 3] = wv.w;
        __syncthreads();

        #pragma unroll
        for (int kk = 0; kk < 16; ++kk) {
            float a[4], b[4];
            #pragma unroll
            for (int i = 0; i < 4; ++i) a[i] = Xs[ty + (i << 4)][kk];
            #pragma unroll
            for (int j = 0; j < 4; ++j) b[j] = Ws[tx + (j << 4)][kk];
            #pragma unroll
            for (int i = 0; i < 4; ++i)
                #pragma unroll
                for (int j = 0; j < 4; ++j)
                    acc[i][j] = fmaf(a[i], b[j], acc[i][j]);
        }
        __syncthreads();
    }

    #pragma unroll
    for (int i = 0; i < 4; ++i) {
        const int m = m0 + ty + (i << 4);
        #pragma unroll
        for (int j = 0; j < 4; ++j) {
            const int n = n0 + tx + (j << 4);
            Y[(size_t)m * N + n] = acc[i][j] + bias[n];
        }
    }
}

// ---------------------------------------------------------------------------
// Same GEMM, but output is fp16 in split-head layout [B,H,S,HD].
// ---------------------------------------------------------------------------
__global__ __launch_bounds__(256) void gemm_bias_h(
    const float* __restrict__ X, const float* __restrict__ W,
    const float* __restrict__ bias, _Float16* __restrict__ Y,
    int M, int N, int K)
{
    __shared__ float Xs[64][17];
    __shared__ float Ws[64][17];

    const int tid = threadIdx.x;
    const int tx = tid & 15;
    const int ty = tid >> 4;
    const int m0 = blockIdx.y << 6;
    const int n0 = blockIdx.x << 6;
    const int lrow = tid >> 2;
    const int lcol = (tid & 3) << 2;

    float acc[4][4] = {};

    for (int k0 = 0; k0 < K; k0 += 16) {
        const float4 xv = *reinterpret_cast<const float4*>(
            &X[(size_t)(m0 + lrow) * K + k0 + lcol]);
        const float4 wv = *reinterpret_cast<const float4*>(
            &W[(size_t)(n0 + lrow) * K + k0 + lcol]);
        Xs[lrow][lcol + 0] = xv.x; Xs[lrow][lcol + 1] = xv.y;
        Xs[lrow][lcol + 2] = xv.z; Xs[lrow][lcol + 3] = xv.w;
        Ws[lrow][lcol + 0] = wv.x; Ws[lrow][lcol + 1] = wv.y;
        Ws[lrow][lcol + 2] = wv.z; Ws[lrow][lcol + 3] = wv.w;
        __syncthreads();

        #pragma unroll
        for (int kk = 0; kk < 16; ++kk) {
            float a[4], b[4];
            #pragma unroll
            for (int i = 0; i < 4; ++i) a[i] = Xs[ty + (i << 4)][kk];
            #pragma unroll
            for (int j = 0; j < 4; ++j) b[j] = Ws[tx + (j << 4)][kk];
            #pragma unroll
            for (int i = 0; i < 4; ++i)
                #pragma unroll
                for (int j = 0; j < 4; ++j)
                    acc[i][j] = fmaf(a[i], b[j], acc[i][j]);
        }
        __syncthreads();
    }

    #pragma unroll
    for (int i = 0; i < 4; ++i) {
        const int m = m0 + ty + (i << 4);
        #pragma unroll
        for (int j = 0; j < 4; ++j) {
            const int n = n0 + tx + (j << 4);
            const float v = acc[i][j] + bias[n];
            const int b_ = m >> 11;           // m / S
            const int s_ = m & (SS - 1);
            const int h_ = n >> 6;            // n / HD
            const int d_ = n & (HDIM - 1);
            Y[(((size_t)(b_ * HH + h_)) * SS + s_) * HDIM + d_] = (_Float16)v;
        }
    }
}

// ---------------------------------------------------------------------------
// MFMA fp16 flash attention (swapped operands).
// Grid: (S/64, B*H), block 256 = 4 waves; wave w handles 16 q-rows.
// Per 64-key tile:  S^T = mfma(K, Q)  (2x 16x16x32 per 16-key group)
//   -> online softmax fully in-register (C/D layout: key=(l>>4)*4+r, q=l&15)
//   -> P^T (C/D layout) IS the PV B-operand fragment (stacked k-pattern)
//   -> O^T += mfma(V^T, P^T); V^T staged transposed in LDS.
// ---------------------------------------------------------------------------
__global__ __launch_bounds__(256) void attn_mfma_kernel(
    const _Float16* __restrict__ Qh, const _Float16* __restrict__ Kh,
    const _Float16* __restrict__ Vh, const int* __restrict__ mask,
    float* __restrict__ AO)
{
    __shared__ _Float16 Ks[64][72];   // [key][d]
    __shared__ _Float16 VTs[64][72];  // [d][key]

    const int tid  = threadIdx.x;
    const int lane = tid & 63;
    const int wq   = tid >> 6;         // wave 0..3
    const int bh   = blockIdx.y;
    const int b_   = bh >> 4;
    const int h_   = bh & (HH - 1);
    const int q0   = blockIdx.x << 6;  // 64 q rows / block

    const int lr = lane & 15;          // fragment row index
    const int lg = lane >> 4;          // lane group 0..3

    // Q fragments, kept in registers for the whole kernel. Contiguous
    // k-pattern (lg*8 + e) — shared by A and B of QK^T, so any true HW
    // permutation cancels.
    const int qrow = q0 + wq * 16 + lr;
    const _Float16* qbase = Qh + ((size_t)bh * SS + qrow) * HDIM;
    const f16x8 qf0 = *reinterpret_cast<const f16x8*>(qbase + lg * 8);
    const f16x8 qf1 = *reinterpret_cast<const f16x8*>(qbase + 32 + lg * 8);

    float m_run = -INFINITY;
    float l_run = 0.0f;
    f32x4 oacc[4];
    #pragma unroll
    for (int dc = 0; dc < 4; ++dc) oacc[dc] = (f32x4){0.f, 0.f, 0.f, 0.f};

    // cooperative staging indices
    const int skey = tid >> 2;          // 0..63
    const int sd0  = (tid & 3) << 4;    // 0,16,32,48
    const _Float16* kglob = Kh + (size_t)bh * SS * HDIM;
    const _Float16* vglob = Vh + (size_t)bh * SS * HDIM;

    const int* mbase = mask + ((size_t)b_ * SS + qrow) * SS;  // per-lane q row

    for (int kt = 0; kt < SS; kt += 64) {
        // ---- stage K (row-major) and V^T (transposed) into LDS ----
        {
            const f16x8* ks = reinterpret_cast<const f16x8*>(
                kglob + (size_t)(kt + skey) * HDIM + sd0);
            const f16x8 ka = ks[0], kb2 = ks[1];
            *reinterpret_cast<f16x8*>(&Ks[skey][sd0])     = ka;
            *reinterpret_cast<f16x8*>(&Ks[skey][sd0 + 8]) = kb2;

            const f16x8* vs = reinterpret_cast<const f16x8*>(
                vglob + (size_t)(kt + skey) * HDIM + sd0);
            const f16x8 va = vs[0], vb = vs[1];
            #pragma unroll
            for (int i = 0; i < 8; ++i) VTs[sd0 + i][skey] = va[i];
            #pragma unroll
            for (int i = 0; i < 8; ++i) VTs[sd0 + 8 + i][skey] = vb[i];
        }
        __syncthreads();

        // ---- QK^T: S^T[key][q] for 4 key-groups of 16 ----
        f32x4 sarr[4];
        #pragma unroll
        for (int kg = 0; kg < 4; ++kg) {
            const _Float16* krow = &Ks[kg * 16 + lr][lg * 8];
            const f16x8 kf0 = *reinterpret_cast<const f16x8*>(krow);
            const f16x8 kf1 = *reinterpret_cast<const f16x8*>(krow + 32);
            f32x4 acc = (f32x4){0.f, 0.f, 0.f, 0.f};
            acc = __builtin_amdgcn_mfma_f32_16x16x32_f16(kf0, qf0, acc, 0, 0, 0);
            acc = __builtin_amdgcn_mfma_f32_16x16x32_f16(kf1, qf1, acc, 0, 0, 0);
            sarr[kg] = acc;
        }

        // ---- scale + mask ----
        float sv[16];
        #pragma unroll
        for (int kg = 0; kg < 4; ++kg) {
            const int4 mv = *reinterpret_cast<const int4*>(
                mbase + kt + kg * 16 + lg * 4);
            sv[4 * kg + 0] = (mv.x == 0) ? -1e9f : sarr[kg][0] * 0.125f;
            sv[4 * kg + 1] = (mv.y == 0) ? -1e9f : sarr[kg][1] * 0.125f;
            sv[4 * kg + 2] = (mv.z == 0) ? -1e9f : sarr[kg][2] * 0.125f;
            sv[4 * kg + 3] = (mv.w == 0) ? -1e9f : sarr[kg][3] * 0.125f;
        }

        // ---- online softmax (per q = per lane column) ----
        float tm = sv[0];
        #pragma unroll
        for (int i = 1; i < 16; ++i) tm = fmaxf(tm, sv[i]);
        tm = fmaxf(tm, __shfl_xor(tm, 16));
        tm = fmaxf(tm, __shfl_xor(tm, 32));
        const float m_new = fmaxf(m_run, tm);
        const float corr  = __expf(m_run - m_new);

        float p[16];
        float psum = 0.f;
        #pragma unroll
        for (int i = 0; i < 16; ++i) { p[i] = __expf(sv[i] - m_new); psum += p[i]; }
        psum += __shfl_xor(psum, 16);
        psum += __shfl_xor(psum, 32);
        l_run = l_run * corr + psum;
        m_run = m_new;
        #pragma unroll
        for (int dc = 0; dc < 4; ++dc) oacc[dc] *= corr;

        // ---- P^T -> fp16 B-fragments (direct from C/D layout) ----
        f16x8 pb0, pb1;
        #pragma unroll
        for (int e = 0; e < 8; ++e) { pb0[e] = (_Float16)p[e]; pb1[e] = (_Float16)p[8 + e]; }

        // ---- PV: O^T += V^T * P^T ----
        #pragma unroll
        for (int dc = 0; dc < 4; ++dc) {
            const _Float16* vrow = &VTs[dc * 16 + lr][lg * 4];
            const f16x4 a0 = *reinterpret_cast<const f16x4*>(vrow);        // keys  0..15 grp
            const f16x4 a1 = *reinterpret_cast<const f16x4*>(vrow + 16);
            const f16x4 a2 = *reinterpret_cast<const f16x4*>(vrow + 32);
            const f16x4 a3 = *reinterpret_cast<const f16x4*>(vrow + 48);
            const f16x8 va0 = __builtin_shufflevector(a0, a1, 0, 1, 2, 3, 4, 5, 6, 7);
            const f16x8 va1 = __builtin_shufflevector(a2, a3, 0, 1, 2, 3, 4, 5, 6, 7);
            oacc[dc] = __builtin_amdgcn_mfma_f32_16x16x32_f16(va0, pb0, oacc[dc], 0, 0, 0);
            oacc[dc] = __builtin_amdgcn_mfma_f32_16x16x32_f16(va1, pb1, oacc[dc], 0, 0, 0);
        }
        __syncthreads();
    }

    // ---- epilogue: O[q][d] = O^T / l ----
    const float invl = 1.0f / l_run;
    float* obase = AO + ((size_t)b_ * SS + qrow) * DD + h_ * HDIM;
    #pragma unroll
    for (int dc = 0; dc < 4; ++dc) {
        f32x4 r = oacc[dc];
        r[0] *= invl; r[1] *= invl; r[2] *= invl; r[3] *= invl;
        *reinterpret_cast<f32x4*>(obase + dc * 16 + lg * 4) = r;
    }
}

// ---------------------------------------------------------------------------
extern "C" void kernel_launch(void* const* d_in, const int* in_sizes, int n_in,
                              void* d_out, int out_size, void* d_ws, size_t ws_size,
                              hipStream_t stream)
{
    const float* q    = (const float*)d_in[0];
    const float* k    = (const float*)d_in[1];
    const float* v    = (const float*)d_in[2];
    const int*   mask = (const int*)d_in[3];
    const float* Wq   = (const float*)d_in[4];
    const float* bq   = (const float*)d_in[5];
    const float* Wk   = (const float*)d_in[6];
    const float* bk   = (const float*)d_in[7];
    const float* Wv   = (const float*)d_in[8];
    const float* bv   = (const float*)d_in[9];
    const float* Wo   = (const float*)d_in[10];
    const float* bo   = (const float*)d_in[11];
    float* out = (float*)d_out;

    const size_t per = (size_t)BB * HH * SS * HDIM;   // 4,194,304
    _Float16* Qh = (_Float16*)d_ws;
    _Float16* Kh = Qh + per;
    _Float16* Vh = Kh + per;
    float*    AO = (float*)((char*)d_ws + 3 * per * sizeof(_Float16));

    const dim3 gblk(DD / 64, (BB * SS) / 64);         // (16, 64)
    gemm_bias_h<<<gblk, 256, 0, stream>>>(q, Wq, bq, Qh, BB * SS, DD, DD);
    gemm_bias_h<<<gblk, 256, 0, stream>>>(k, Wk, bk, Kh, BB * SS, DD, DD);
    gemm_bias_h<<<gblk, 256, 0, stream>>>(v, Wv, bv, Vh, BB * SS, DD, DD);

    const dim3 gattn(SS / 64, BB * HH);               // (32, 32)
    attn_mfma_kernel<<<gattn, 256, 0, stream>>>(Qh, Kh, Vh, mask, AO);

    gemm_bias_f32<<<gblk, 256, 0, stream>>>(AO, Wo, bo, out, BB * SS, DD, DD);
}

// Round 3
// 215.401 us; speedup vs baseline: 10.8622x; 3.5098x over previous
//
#include <hip/hip_runtime.h>
#include <math.h>

#define BB 2
#define SS 2048
#define DD 1024
#define HH 16
#define HDIM 64
#define KK 1024           // GEMM K  (= D)
#define MM 4096           // GEMM M  (= B*S)

typedef _Float16 f16x4 __attribute__((ext_vector_type(4)));
typedef _Float16 f16x8 __attribute__((ext_vector_type(8)));
typedef float    f32x4 __attribute__((ext_vector_type(4)));

#define GLL16(gp, lp) __builtin_amdgcn_global_load_lds(                        \
    (const __attribute__((address_space(1))) void*)(gp),                       \
    (__attribute__((address_space(3))) void*)(lp), 16, 0, 0)

// ---------------------------------------------------------------------------
// Fused fp32 -> fp16 convert of q,k,v (4M elems each) + Wq,Wk,Wv,Wo (1M each).
// One thread = one float4 -> f16x4.  Total 16M elements / 4 = 4M threads.
// Tensor boundaries are multiples of 256K units -> wave-uniform branches.
// ---------------------------------------------------------------------------
__global__ __launch_bounds__(256) void cvt_all(
    const float* __restrict__ q,  const float* __restrict__ k,
    const float* __restrict__ v,  const float* __restrict__ wq,
    const float* __restrict__ wk, const float* __restrict__ wv,
    const float* __restrict__ wo,
    _Float16* __restrict__ qh,  _Float16* __restrict__ kh,
    _Float16* __restrict__ vh,  _Float16* __restrict__ wqh,
    _Float16* __restrict__ wkh, _Float16* __restrict__ wvh,
    _Float16* __restrict__ woh)
{
    const unsigned u  = blockIdx.x * 256u + threadIdx.x;  // float4 units
    const unsigned U1 = 1u << 20;                          // 4M floats / 4
    const unsigned U2 = 1u << 18;                          // 1M floats / 4
    const float* src; _Float16* dst; unsigned off;
    if (u < 3u * U1) {
        const unsigned t = u >> 20; off = u & (U1 - 1u);
        src = (t == 0) ? q  : (t == 1) ? k  : v;
        dst = (t == 0) ? qh : (t == 1) ? kh : vh;
    } else {
        const unsigned r = u - 3u * U1;
        const unsigned t = r >> 18; off = r & (U2 - 1u);
        src = (t == 0) ? wq  : (t == 1) ? wk  : (t == 2) ? wv  : wo;
        dst = (t == 0) ? wqh : (t == 1) ? wkh : (t == 2) ? wvh : woh;
    }
    const float4 x = ((const float4*)src)[off];
    f16x4 y;
    y[0] = (_Float16)x.x; y[1] = (_Float16)x.y;
    y[2] = (_Float16)x.z; y[3] = (_Float16)x.w;
    ((f16x4*)dst)[off] = y;
}

// ---------------------------------------------------------------------------
// MFMA GEMM: Y = X @ W^T + bias.  X[M,K] fp16, W[N,K] fp16, fp32 accum.
// Tile 128x64, BK=32, 256 threads = 4 waves (2x2), wave tile 64x32 (4x2 frags).
// Staging via global_load_lds (16B), linear LDS, 2-barrier K-loop (m97 style).
// LAYOUT 0: fp32 Y[m*DD+n].  LAYOUT 1: fp16 split-head [B,H,S,HD].
// ---------------------------------------------------------------------------
template <int LAYOUT>
__global__ __launch_bounds__(256) void gemm_mfma(
    const _Float16* __restrict__ X, const _Float16* __restrict__ W,
    const float* __restrict__ bias, void* __restrict__ Yout)
{
    __shared__ _Float16 As[128 * 32];   // 8 KB, row stride 64 B
    __shared__ _Float16 Bs[64 * 32];    // 4 KB

    const int tid  = threadIdx.x;
    const int lane = tid & 63;
    const int lr   = lane & 15;
    const int lg   = lane >> 4;
    const int wave = tid >> 6;
    const int wr   = wave >> 1;         // 0..1 -> m-offset wr*64
    const int wc   = wave & 1;          // 0..1 -> n-offset wc*32

    const int m0 = blockIdx.y << 7;
    const int n0 = blockIdx.x << 6;

    const char* Xb = (const char*)X;
    const char* Wb = (const char*)W;

    // staging: A needs 8KB = 2 chunks/thread of 16B, B needs 4KB = 1 chunk.
    const int pa0 = tid * 16;           // LDS byte offset, chunk 0
    const int pa1 = pa0 + 4096;
    const int ra0 = pa0 >> 6, ca0 = pa0 & 63;
    const int ra1 = pa1 >> 6, ca1 = pa1 & 63;
    const int rb0 = pa0 >> 6, cb0 = pa0 & 63;   // Bs rows 0..63

    f32x4 acc[4][2] = {};

    for (int k0 = 0; k0 < KK; k0 += 32) {
        GLL16(Xb + ((size_t)(m0 + ra0) * KK + k0) * 2 + ca0, (char*)As + pa0);
        GLL16(Xb + ((size_t)(m0 + ra1) * KK + k0) * 2 + ca1, (char*)As + pa1);
        GLL16(Wb + ((size_t)(n0 + rb0) * KK + k0) * 2 + cb0, (char*)Bs + pa0);
        __syncthreads();    // drains vmcnt -> staged tile visible

        f16x8 af[4], bf[2];
        #pragma unroll
        for (int mi = 0; mi < 4; ++mi)
            af[mi] = *(const f16x8*)((const char*)As +
                       ((wr * 64 + mi * 16 + lr) * 64 + lg * 16));
        #pragma unroll
        for (int ni = 0; ni < 2; ++ni)
            bf[ni] = *(const f16x8*)((const char*)Bs +
                       ((wc * 32 + ni * 16 + lr) * 64 + lg * 16));

        #pragma unroll
        for (int mi = 0; mi < 4; ++mi)
            #pragma unroll
            for (int ni = 0; ni < 2; ++ni)
                acc[mi][ni] = __builtin_amdgcn_mfma_f32_16x16x32_f16(
                    af[mi], bf[ni], acc[mi][ni], 0, 0, 0);
        __syncthreads();    // all reads done before next stage overwrites
    }

    // epilogue: C/D layout col = lane&15 -> n, row = lg*4 + reg -> m
    #pragma unroll
    for (int ni = 0; ni < 2; ++ni) {
        const int n  = n0 + wc * 32 + ni * 16 + lr;
        const float bv = bias[n];
        #pragma unroll
        for (int mi = 0; mi < 4; ++mi) {
            #pragma unroll
            for (int r = 0; r < 4; ++r) {
                const int m = m0 + wr * 64 + mi * 16 + lg * 4 + r;
                const float y = acc[mi][ni][r] + bv;
                if (LAYOUT == 0) {
                    ((float*)Yout)[(size_t)m * DD + n] = y;
                } else {
                    const int b_ = m >> 11;
                    const int s_ = m & (SS - 1);
                    const int h_ = n >> 6;
                    const int d_ = n & (HDIM - 1);
                    ((_Float16*)Yout)[(((size_t)(b_ * HH + h_)) * SS + s_) * HDIM + d_] =
                        (_Float16)y;
                }
            }
        }
    }
}

// ---------------------------------------------------------------------------
// MFMA fp16 flash attention (swapped operands), unchanged from round 2 except
// AO is now written as fp16 (feeds the fp16 MFMA output projection directly).
// ---------------------------------------------------------------------------
__global__ __launch_bounds__(256) void attn_mfma_kernel(
    const _Float16* __restrict__ Qh, const _Float16* __restrict__ Kh,
    const _Float16* __restrict__ Vh, const int* __restrict__ mask,
    _Float16* __restrict__ AO)
{
    __shared__ _Float16 Ks[64][72];   // [key][d]
    __shared__ _Float16 VTs[64][72];  // [d][key]

    const int tid  = threadIdx.x;
    const int lane = tid & 63;
    const int wq   = tid >> 6;
    const int bh   = blockIdx.y;
    const int b_   = bh >> 4;
    const int h_   = bh & (HH - 1);
    const int q0   = blockIdx.x << 6;

    const int lr = lane & 15;
    const int lg = lane >> 4;

    const int qrow = q0 + wq * 16 + lr;
    const _Float16* qbase = Qh + ((size_t)bh * SS + qrow) * HDIM;
    const f16x8 qf0 = *reinterpret_cast<const f16x8*>(qbase + lg * 8);
    const f16x8 qf1 = *reinterpret_cast<const f16x8*>(qbase + 32 + lg * 8);

    float m_run = -INFINITY;
    float l_run = 0.0f;
    f32x4 oacc[4];
    #pragma unroll
    for (int dc = 0; dc < 4; ++dc) oacc[dc] = (f32x4){0.f, 0.f, 0.f, 0.f};

    const int skey = tid >> 2;
    const int sd0  = (tid & 3) << 4;
    const _Float16* kglob = Kh + (size_t)bh * SS * HDIM;
    const _Float16* vglob = Vh + (size_t)bh * SS * HDIM;

    const int* mbase = mask + ((size_t)b_ * SS + qrow) * SS;

    for (int kt = 0; kt < SS; kt += 64) {
        {
            const f16x8* ks = reinterpret_cast<const f16x8*>(
                kglob + (size_t)(kt + skey) * HDIM + sd0);
            const f16x8 ka = ks[0], kb2 = ks[1];
            *reinterpret_cast<f16x8*>(&Ks[skey][sd0])     = ka;
            *reinterpret_cast<f16x8*>(&Ks[skey][sd0 + 8]) = kb2;

            const f16x8* vs = reinterpret_cast<const f16x8*>(
                vglob + (size_t)(kt + skey) * HDIM + sd0);
            const f16x8 va = vs[0], vb = vs[1];
            #pragma unroll
            for (int i = 0; i < 8; ++i) VTs[sd0 + i][skey] = va[i];
            #pragma unroll
            for (int i = 0; i < 8; ++i) VTs[sd0 + 8 + i][skey] = vb[i];
        }
        __syncthreads();

        f32x4 sarr[4];
        #pragma unroll
        for (int kg = 0; kg < 4; ++kg) {
            const _Float16* krow = &Ks[kg * 16 + lr][lg * 8];
            const f16x8 kf0 = *reinterpret_cast<const f16x8*>(krow);
            const f16x8 kf1 = *reinterpret_cast<const f16x8*>(krow + 32);
            f32x4 a = (f32x4){0.f, 0.f, 0.f, 0.f};
            a = __builtin_amdgcn_mfma_f32_16x16x32_f16(kf0, qf0, a, 0, 0, 0);
            a = __builtin_amdgcn_mfma_f32_16x16x32_f16(kf1, qf1, a, 0, 0, 0);
            sarr[kg] = a;
        }

        float sv[16];
        #pragma unroll
        for (int kg = 0; kg < 4; ++kg) {
            const int4 mv = *reinterpret_cast<const int4*>(
                mbase + kt + kg * 16 + lg * 4);
            sv[4 * kg + 0] = (mv.x == 0) ? -1e9f : sarr[kg][0] * 0.125f;
            sv[4 * kg + 1] = (mv.y == 0) ? -1e9f : sarr[kg][1] * 0.125f;
            sv[4 * kg + 2] = (mv.z == 0) ? -1e9f : sarr[kg][2] * 0.125f;
            sv[4 * kg + 3] = (mv.w == 0) ? -1e9f : sarr[kg][3] * 0.125f;
        }

        float tm = sv[0];
        #pragma unroll
        for (int i = 1; i < 16; ++i) tm = fmaxf(tm, sv[i]);
        tm = fmaxf(tm, __shfl_xor(tm, 16));
        tm = fmaxf(tm, __shfl_xor(tm, 32));
        const float m_new = fmaxf(m_run, tm);
        const float corr  = __expf(m_run - m_new);

        float p[16];
        float psum = 0.f;
        #pragma unroll
        for (int i = 0; i < 16; ++i) { p[i] = __expf(sv[i] - m_new); psum += p[i]; }
        psum += __shfl_xor(psum, 16);
        psum += __shfl_xor(psum, 32);
        l_run = l_run * corr + psum;
        m_run = m_new;
        #pragma unroll
        for (int dc = 0; dc < 4; ++dc) oacc[dc] *= corr;

        f16x8 pb0, pb1;
        #pragma unroll
        for (int e = 0; e < 8; ++e) { pb0[e] = (_Float16)p[e]; pb1[e] = (_Float16)p[8 + e]; }

        #pragma unroll
        for (int dc = 0; dc < 4; ++dc) {
            const _Float16* vrow = &VTs[dc * 16 + lr][lg * 4];
            const f16x4 a0 = *reinterpret_cast<const f16x4*>(vrow);
            const f16x4 a1 = *reinterpret_cast<const f16x4*>(vrow + 16);
            const f16x4 a2 = *reinterpret_cast<const f16x4*>(vrow + 32);
            const f16x4 a3 = *reinterpret_cast<const f16x4*>(vrow + 48);
            const f16x8 va0 = __builtin_shufflevector(a0, a1, 0, 1, 2, 3, 4, 5, 6, 7);
            const f16x8 va1 = __builtin_shufflevector(a2, a3, 0, 1, 2, 3, 4, 5, 6, 7);
            oacc[dc] = __builtin_amdgcn_mfma_f32_16x16x32_f16(va0, pb0, oacc[dc], 0, 0, 0);
            oacc[dc] = __builtin_amdgcn_mfma_f32_16x16x32_f16(va1, pb1, oacc[dc], 0, 0, 0);
        }
        __syncthreads();
    }

    const float invl = 1.0f / l_run;
    _Float16* obase = AO + ((size_t)b_ * SS + qrow) * DD + h_ * HDIM;
    #pragma unroll
    for (int dc = 0; dc < 4; ++dc) {
        f16x4 r;
        r[0] = (_Float16)(oacc[dc][0] * invl);
        r[1] = (_Float16)(oacc[dc][1] * invl);
        r[2] = (_Float16)(oacc[dc][2] * invl);
        r[3] = (_Float16)(oacc[dc][3] * invl);
        *reinterpret_cast<f16x4*>(obase + dc * 16 + lg * 4) = r;
    }
}

// ---------------------------------------------------------------------------
extern "C" void kernel_launch(void* const* d_in, const int* in_sizes, int n_in,
                              void* d_out, int out_size, void* d_ws, size_t ws_size,
                              hipStream_t stream)
{
    const float* q    = (const float*)d_in[0];
    const float* k    = (const float*)d_in[1];
    const float* v    = (const float*)d_in[2];
    const int*   mask = (const int*)d_in[3];
    const float* Wq   = (const float*)d_in[4];
    const float* bq   = (const float*)d_in[5];
    const float* Wk   = (const float*)d_in[6];
    const float* bk   = (const float*)d_in[7];
    const float* Wv   = (const float*)d_in[8];
    const float* bv   = (const float*)d_in[9];
    const float* Wo   = (const float*)d_in[10];
    const float* bo   = (const float*)d_in[11];
    float* out = (float*)d_out;

    const size_t per  = (size_t)BB * SS * DD;   // 4,194,304 elements
    const size_t wsz  = (size_t)DD * DD;        // 1,048,576 elements
    char* w = (char*)d_ws;
    _Float16* qx  = (_Float16*)(w);                       // 8 MB
    _Float16* kx  = (_Float16*)(w + 8  * 1048576);
    _Float16* vx  = (_Float16*)(w + 16 * 1048576);
    _Float16* wqh = (_Float16*)(w + 24 * 1048576);        // 2 MB each
    _Float16* wkh = (_Float16*)(w + 26 * 1048576);
    _Float16* wvh = (_Float16*)(w + 28 * 1048576);
    _Float16* woh = (_Float16*)(w + 30 * 1048576);
    _Float16* Qh  = (_Float16*)(w + 32 * 1048576);        // 8 MB each
    _Float16* Kh  = (_Float16*)(w + 40 * 1048576);
    _Float16* Vh  = (_Float16*)(w + 48 * 1048576);
    _Float16* AO  = (_Float16*)(w + 56 * 1048576);        // 8 MB
    (void)per; (void)wsz;

    cvt_all<<<16384, 256, 0, stream>>>(q, k, v, Wq, Wk, Wv, Wo,
                                       qx, kx, vx, wqh, wkh, wvh, woh);

    const dim3 gblk(DD / 64, MM / 128);          // (16, 32) = 512 blocks
    gemm_mfma<1><<<gblk, 256, 0, stream>>>(qx, wqh, bq, Qh);
    gemm_mfma<1><<<gblk, 256, 0, stream>>>(kx, wkh, bk, Kh);
    gemm_mfma<1><<<gblk, 256, 0, stream>>>(vx, wvh, bv, Vh);

    const dim3 gattn(SS / 64, BB * HH);          // (32, 32)
    attn_mfma_kernel<<<gattn, 256, 0, stream>>>(Qh, Kh, Vh, mask, AO);

    gemm_mfma<0><<<gblk, 256, 0, stream>>>(AO, woh, bo, out);
}

// Round 4
// 203.702 us; speedup vs baseline: 11.4860x; 1.0574x over previous
//
#include <hip/hip_runtime.h>
#include <math.h>

#define BB 2
#define SS 2048
#define DD 1024
#define HH 16
#define HDIM 64
#define KK 1024           // GEMM K  (= D)
#define MM 4096           // GEMM M  (= B*S)

typedef _Float16 f16x4 __attribute__((ext_vector_type(4)));
typedef _Float16 f16x8 __attribute__((ext_vector_type(8)));
typedef float    f32x4 __attribute__((ext_vector_type(4)));

#define GLL16(gp, lp) __builtin_amdgcn_global_load_lds(                        \
    (const __attribute__((address_space(1))) void*)(gp),                       \
    (__attribute__((address_space(3))) void*)(lp), 16, 0, 0)

// ---------------------------------------------------------------------------
// Fused fp32 -> fp16 convert of q,k,v (4M each) + Wq,Wk,Wv,Wo (1M each).
// ---------------------------------------------------------------------------
__global__ __launch_bounds__(256) void cvt_all(
    const float* __restrict__ q,  const float* __restrict__ k,
    const float* __restrict__ v,  const float* __restrict__ wq,
    const float* __restrict__ wk, const float* __restrict__ wv,
    const float* __restrict__ wo,
    _Float16* __restrict__ qh,  _Float16* __restrict__ kh,
    _Float16* __restrict__ vh,  _Float16* __restrict__ wqh,
    _Float16* __restrict__ wkh, _Float16* __restrict__ wvh,
    _Float16* __restrict__ woh)
{
    const unsigned u  = blockIdx.x * 256u + threadIdx.x;  // float4 units
    const unsigned U1 = 1u << 20;
    const unsigned U2 = 1u << 18;
    const float* src; _Float16* dst; unsigned off;
    if (u < 3u * U1) {
        const unsigned t = u >> 20; off = u & (U1 - 1u);
        src = (t == 0) ? q  : (t == 1) ? k  : v;
        dst = (t == 0) ? qh : (t == 1) ? kh : vh;
    } else {
        const unsigned r = u - 3u * U1;
        const unsigned t = r >> 18; off = r & (U2 - 1u);
        src = (t == 0) ? wq  : (t == 1) ? wk  : (t == 2) ? wv  : wo;
        dst = (t == 0) ? wqh : (t == 1) ? wkh : (t == 2) ? wvh : woh;
    }
    const float4 x = ((const float4*)src)[off];
    f16x4 y;
    y[0] = (_Float16)x.x; y[1] = (_Float16)x.y;
    y[2] = (_Float16)x.z; y[3] = (_Float16)x.w;
    ((f16x4*)dst)[off] = y;
}

// ---------------------------------------------------------------------------
// Pack mask [B,1,S,S] int32 -> 1 bit per key.  u16 #t covers ints 16t..16t+15
// (little-endian => u64 word w has bit j = key j of 64-key tile w).
// ---------------------------------------------------------------------------
__global__ __launch_bounds__(256) void mask_bits(
    const int* __restrict__ mask, unsigned short* __restrict__ bm16)
{
    const size_t t = (size_t)blockIdx.x * 256 + threadIdx.x;  // 0..524287
    const int4* p = (const int4*)(mask + t * 16);
    const int4 a = p[0], b = p[1], c = p[2], d = p[3];
    unsigned v = 0;
    v |= (a.x != 0) << 0;  v |= (a.y != 0) << 1;
    v |= (a.z != 0) << 2;  v |= (a.w != 0) << 3;
    v |= (b.x != 0) << 4;  v |= (b.y != 0) << 5;
    v |= (b.z != 0) << 6;  v |= (b.w != 0) << 7;
    v |= (c.x != 0) << 8;  v |= (c.y != 0) << 9;
    v |= (c.z != 0) << 10; v |= (c.w != 0) << 11;
    v |= (d.x != 0) << 12; v |= (d.y != 0) << 13;
    v |= (d.z != 0) << 14; v |= (d.w != 0) << 15;
    bm16[t] = (unsigned short)v;
}

// ---------------------------------------------------------------------------
// MFMA GEMM: Y = X @ W^T + bias.  X[M,K] fp16, W[N,K] fp16, fp32 accum.
// Tile 128x64, BK=32, 4 waves (2x2).  global_load_lds staging, linear LDS.
// LAYOUT 0: fp32 Y[m*DD+n]
// LAYOUT 1: fp16 split-head [B,H,S,HD]
// LAYOUT 2: fp16 transposed  [B,H,HD,S]   (for V -> attention A-operand)
// ---------------------------------------------------------------------------
template <int LAYOUT>
__global__ __launch_bounds__(256) void gemm_mfma(
    const _Float16* __restrict__ X, const _Float16* __restrict__ W,
    const float* __restrict__ bias, void* __restrict__ Yout)
{
    __shared__ _Float16 As[128 * 32];   // 8 KB
    __shared__ _Float16 Bs[64 * 32];    // 4 KB

    const int tid  = threadIdx.x;
    const int lane = tid & 63;
    const int lr   = lane & 15;
    const int lg   = lane >> 4;
    const int wave = tid >> 6;
    const int wr   = wave >> 1;
    const int wc   = wave & 1;

    const int m0 = blockIdx.y << 7;
    const int n0 = blockIdx.x << 6;

    const char* Xb = (const char*)X;
    const char* Wb = (const char*)W;

    const int pa0 = tid * 16;
    const int pa1 = pa0 + 4096;
    const int ra0 = pa0 >> 6, ca0 = pa0 & 63;
    const int ra1 = pa1 >> 6, ca1 = pa1 & 63;
    const int rb0 = pa0 >> 6, cb0 = pa0 & 63;

    f32x4 acc[4][2] = {};

    for (int k0 = 0; k0 < KK; k0 += 32) {
        GLL16(Xb + ((size_t)(m0 + ra0) * KK + k0) * 2 + ca0, (char*)As + pa0);
        GLL16(Xb + ((size_t)(m0 + ra1) * KK + k0) * 2 + ca1, (char*)As + pa1);
        GLL16(Wb + ((size_t)(n0 + rb0) * KK + k0) * 2 + cb0, (char*)Bs + pa0);
        __syncthreads();

        f16x8 af[4], bf[2];
        #pragma unroll
        for (int mi = 0; mi < 4; ++mi)
            af[mi] = *(const f16x8*)((const char*)As +
                       ((wr * 64 + mi * 16 + lr) * 64 + lg * 16));
        #pragma unroll
        for (int ni = 0; ni < 2; ++ni)
            bf[ni] = *(const f16x8*)((const char*)Bs +
                       ((wc * 32 + ni * 16 + lr) * 64 + lg * 16));

        #pragma unroll
        for (int mi = 0; mi < 4; ++mi)
            #pragma unroll
            for (int ni = 0; ni < 2; ++ni)
                acc[mi][ni] = __builtin_amdgcn_mfma_f32_16x16x32_f16(
                    af[mi], bf[ni], acc[mi][ni], 0, 0, 0);
        __syncthreads();
    }

    #pragma unroll
    for (int ni = 0; ni < 2; ++ni) {
        const int n  = n0 + wc * 32 + ni * 16 + lr;
        const float bv = bias[n];
        #pragma unroll
        for (int mi = 0; mi < 4; ++mi) {
            const int mbase = m0 + wr * 64 + mi * 16 + lg * 4;
            if (LAYOUT == 0) {
                #pragma unroll
                for (int r = 0; r < 4; ++r)
                    ((float*)Yout)[(size_t)(mbase + r) * DD + n] =
                        acc[mi][ni][r] + bv;
            } else if (LAYOUT == 1) {
                #pragma unroll
                for (int r = 0; r < 4; ++r) {
                    const int m = mbase + r;
                    const int b_ = m >> 11, s_ = m & (SS - 1);
                    const int h_ = n >> 6,  d_ = n & (HDIM - 1);
                    ((_Float16*)Yout)[(((size_t)(b_ * HH + h_)) * SS + s_) * HDIM + d_] =
                        (_Float16)(acc[mi][ni][r] + bv);
                }
            } else {
                const int b_ = mbase >> 11, s_ = mbase & (SS - 1);
                const int h_ = n >> 6,      d_ = n & (HDIM - 1);
                f16x4 tv;
                #pragma unroll
                for (int r = 0; r < 4; ++r) tv[r] = (_Float16)(acc[mi][ni][r] + bv);
                *(f16x4*)((_Float16*)Yout +
                          (((size_t)(b_ * HH + h_)) * HDIM + d_) * SS + s_) = tv;
            }
        }
    }
}

// ---------------------------------------------------------------------------
// MFMA fp16 flash attention, v2.
// Grid (S/64, B*H), 4 waves.  K and V^T staged via global_load_lds into
// XOR-swizzled linear LDS (inverse swizzle on the per-lane GLOBAL address),
// double-buffered, one barrier per tile.  Mask via 1-bit-per-key bitmask.
// ---------------------------------------------------------------------------
__global__ __launch_bounds__(256) void attn_mfma2(
    const _Float16* __restrict__ Qh, const _Float16* __restrict__ Kh,
    const _Float16* __restrict__ Vt, const unsigned long long* __restrict__ bm,
    _Float16* __restrict__ AO)
{
    __shared__ _Float16 KbufS[2][4096];   // [key][64d], rows 128B, swizzled
    __shared__ _Float16 VbufS[2][4096];   // [d][64key], rows 128B, swizzled

    const int tid  = threadIdx.x;
    const int lane = tid & 63;
    const int wq   = tid >> 6;
    const int bh   = blockIdx.y;
    const int b_   = bh >> 4;
    const int h_   = bh & (HH - 1);
    const int q0   = blockIdx.x << 6;
    const int lr   = lane & 15;
    const int lg   = lane >> 4;

    const int qrow = q0 + wq * 16 + lr;
    const _Float16* qbase = Qh + ((size_t)bh * SS + qrow) * HDIM;
    const f16x8 qf0 = *(const f16x8*)(qbase + lg * 8);
    const f16x8 qf1 = *(const f16x8*)(qbase + 32 + lg * 8);

    // --- GLL staging: chunk c (16B) of the 8KB tile; row = c>>3; the LDS is
    // written linearly (base + lane*16); the row-XOR swizzle is applied by
    // pre-swizzling the global source chunk: rc = (c&7) ^ (row&7).
    const int c0 = tid, c1 = tid + 256;
    const int kr0 = c0 >> 3, krc0 = (c0 & 7) ^ (kr0 & 7);
    const int kr1 = c1 >> 3, krc1 = (c1 & 7) ^ (kr1 & 7);
    const _Float16* gK0 = Kh + ((size_t)bh * SS + kr0) * HDIM + krc0 * 8;
    const _Float16* gK1 = Kh + ((size_t)bh * SS + kr1) * HDIM + krc1 * 8;
    const _Float16* gV0 = Vt + ((size_t)bh * HDIM + kr0) * SS + krc0 * 8;
    const _Float16* gV1 = Vt + ((size_t)bh * HDIM + kr1) * SS + krc1 * 8;
    const int woff = (tid >> 6) << 10;   // wave-uniform LDS base (bytes)

    float m_run = -INFINITY, l_run = 0.f;
    f32x4 oacc[4];
    #pragma unroll
    for (int dc = 0; dc < 4; ++dc) oacc[dc] = (f32x4){0.f, 0.f, 0.f, 0.f};

    const unsigned long long* bmrow = bm + ((size_t)b_ * SS + qrow) * (SS / 64);

#define STAGE(KT, BSEL) do {                                                   \
    GLL16(gK0 + (size_t)(KT) * HDIM, (char*)KbufS[BSEL] + woff);               \
    GLL16(gK1 + (size_t)(KT) * HDIM, (char*)KbufS[BSEL] + 4096 + woff);        \
    GLL16(gV0 + (KT), (char*)VbufS[BSEL] + woff);                              \
    GLL16(gV1 + (KT), (char*)VbufS[BSEL] + 4096 + woff);                       \
  } while (0)

    STAGE(0, 0);
    __syncthreads();

    const int xk0 = ((lg       ^ (lr & 7)) << 4);
    const int xk1 = (((4 + lg) ^ (lr & 7)) << 4);
    const int xv  = ((lr & 7) << 4);

    for (int t = 0; t < SS / 64; ++t) {
        const int cur = t & 1;
        if (t < SS / 64 - 1) STAGE((t + 1) * 64, cur ^ 1);

        const char* kb = (const char*)KbufS[cur];
        const char* vb = (const char*)VbufS[cur];
        const unsigned long long bmv = bmrow[t];

        // ---- QK^T ----
        f32x4 sarr[4];
        #pragma unroll
        for (int kg = 0; kg < 4; ++kg) {
            const char* rp = kb + (kg * 16 + lr) * 128;
            const f16x8 kf0 = *(const f16x8*)(rp + xk0);
            const f16x8 kf1 = *(const f16x8*)(rp + xk1);
            f32x4 a = (f32x4){0.f, 0.f, 0.f, 0.f};
            a = __builtin_amdgcn_mfma_f32_16x16x32_f16(kf0, qf0, a, 0, 0, 0);
            a = __builtin_amdgcn_mfma_f32_16x16x32_f16(kf1, qf1, a, 0, 0, 0);
            sarr[kg] = a;
        }

        float sv[16];
        #pragma unroll
        for (int kg = 0; kg < 4; ++kg)
            #pragma unroll
            for (int r = 0; r < 4; ++r)
                sv[kg * 4 + r] = sarr[kg][r] * 0.125f;

        if (~bmv) {   // any masked key (never taken for all-ones mask)
            #pragma unroll
            for (int kg = 0; kg < 4; ++kg)
                #pragma unroll
                for (int r = 0; r < 4; ++r)
                    if (!((bmv >> (kg * 16 + lg * 4 + r)) & 1ull))
                        sv[kg * 4 + r] = -1e9f;
        }

        // ---- online softmax (per q-row = per lane column) ----
        float tm = sv[0];
        #pragma unroll
        for (int i = 1; i < 16; ++i) tm = fmaxf(tm, sv[i]);
        tm = fmaxf(tm, __shfl_xor(tm, 16));
        tm = fmaxf(tm, __shfl_xor(tm, 32));
        const float m_new = fmaxf(m_run, tm);
        const float corr  = __expf(m_run - m_new);

        float p[16];
        float psum = 0.f;
        #pragma unroll
        for (int i = 0; i < 16; ++i) { p[i] = __expf(sv[i] - m_new); psum += p[i]; }
        psum += __shfl_xor(psum, 16);
        psum += __shfl_xor(psum, 32);
        l_run = l_run * corr + psum;
        m_run = m_new;
        #pragma unroll
        for (int dc = 0; dc < 4; ++dc) oacc[dc] *= corr;

        f16x8 pb0, pb1;
        #pragma unroll
        for (int e = 0; e < 8; ++e) { pb0[e] = (_Float16)p[e]; pb1[e] = (_Float16)p[8 + e]; }

        // ---- PV: O^T += V^T * P^T  (k-permutation matches pb exactly) ----
        #pragma unroll
        for (int dc = 0; dc < 4; ++dc) {
            const char* rp = vb + (dc * 16 + lr) * 128;
            const f16x4 a0 = *(const f16x4*)(rp + ((0  + lg * 8) ^ xv));
            const f16x4 a1 = *(const f16x4*)(rp + ((32 + lg * 8) ^ xv));
            const f16x4 a2 = *(const f16x4*)(rp + ((64 + lg * 8) ^ xv));
            const f16x4 a3 = *(const f16x4*)(rp + ((96 + lg * 8) ^ xv));
            const f16x8 va0 = __builtin_shufflevector(a0, a1, 0, 1, 2, 3, 4, 5, 6, 7);
            const f16x8 va1 = __builtin_shufflevector(a2, a3, 0, 1, 2, 3, 4, 5, 6, 7);
            oacc[dc] = __builtin_amdgcn_mfma_f32_16x16x32_f16(va0, pb0, oacc[dc], 0, 0, 0);
            oacc[dc] = __builtin_amdgcn_mfma_f32_16x16x32_f16(va1, pb1, oacc[dc], 0, 0, 0);
        }
        __syncthreads();   // compiler drains vmcnt here -> next tile visible
    }
#undef STAGE

    const float invl = 1.0f / l_run;
    _Float16* obase = AO + ((size_t)b_ * SS + qrow) * DD + h_ * HDIM;
    #pragma unroll
    for (int dc = 0; dc < 4; ++dc) {
        f16x4 r;
        r[0] = (_Float16)(oacc[dc][0] * invl);
        r[1] = (_Float16)(oacc[dc][1] * invl);
        r[2] = (_Float16)(oacc[dc][2] * invl);
        r[3] = (_Float16)(oacc[dc][3] * invl);
        *reinterpret_cast<f16x4*>(obase + dc * 16 + lg * 4) = r;
    }
}

// ---------------------------------------------------------------------------
extern "C" void kernel_launch(void* const* d_in, const int* in_sizes, int n_in,
                              void* d_out, int out_size, void* d_ws, size_t ws_size,
                              hipStream_t stream)
{
    const float* q    = (const float*)d_in[0];
    const float* k    = (const float*)d_in[1];
    const float* v    = (const float*)d_in[2];
    const int*   mask = (const int*)d_in[3];
    const float* Wq   = (const float*)d_in[4];
    const float* bq   = (const float*)d_in[5];
    const float* Wk   = (const float*)d_in[6];
    const float* bk   = (const float*)d_in[7];
    const float* Wv   = (const float*)d_in[8];
    const float* bv   = (const float*)d_in[9];
    const float* Wo   = (const float*)d_in[10];
    const float* bo   = (const float*)d_in[11];
    float* out = (float*)d_out;

    char* w = (char*)d_ws;
    _Float16* qx  = (_Float16*)(w);                       // 8 MB (dead after Q-GEMM)
    _Float16* kx  = (_Float16*)(w + 8  * 1048576);
    _Float16* vx  = (_Float16*)(w + 16 * 1048576);
    _Float16* wqh = (_Float16*)(w + 24 * 1048576);        // 2 MB each
    _Float16* wkh = (_Float16*)(w + 26 * 1048576);
    _Float16* wvh = (_Float16*)(w + 28 * 1048576);
    _Float16* woh = (_Float16*)(w + 30 * 1048576);
    _Float16* Qh  = (_Float16*)(w + 32 * 1048576);        // 8 MB each
    _Float16* Kh  = (_Float16*)(w + 40 * 1048576);
    _Float16* Vt  = (_Float16*)(w + 48 * 1048576);        // [B,H,HD,S]
    _Float16* AO  = (_Float16*)(w + 56 * 1048576);        // 8 MB
    unsigned long long* bm = (unsigned long long*)(w);    // 1 MB, reuses qx

    cvt_all<<<16384, 256, 0, stream>>>(q, k, v, Wq, Wk, Wv, Wo,
                                       qx, kx, vx, wqh, wkh, wvh, woh);

    const dim3 gblk(DD / 64, MM / 128);          // (16, 32) = 512 blocks
    gemm_mfma<1><<<gblk, 256, 0, stream>>>(qx, wqh, bq, Qh);
    gemm_mfma<1><<<gblk, 256, 0, stream>>>(kx, wkh, bk, Kh);
    gemm_mfma<2><<<gblk, 256, 0, stream>>>(vx, wvh, bv, Vt);

    // qx is dead now; pack mask bits into its region.
    mask_bits<<<2048, 256, 0, stream>>>(mask, (unsigned short*)bm);

    const dim3 gattn(SS / 64, BB * HH);          // (32, 32)
    attn_mfma2<<<gattn, 256, 0, stream>>>(Qh, Kh, Vt, bm, AO);

    gemm_mfma<0><<<gblk, 256, 0, stream>>>(AO, woh, bo, out);
}

// Round 5
// 198.367 us; speedup vs baseline: 11.7949x; 1.0269x over previous
//
#include <hip/hip_runtime.h>
#include <math.h>

#define BB 2
#define SS 2048
#define DD 1024
#define HH 16
#define HDIM 64
#define KK 1024           // GEMM K  (= D)
#define MM 4096           // GEMM M  (= B*S)

// 0.125 (1/sqrt(HD)) * log2(e): folds softmax scale+base-change into Wq/bq.
#define QFOLD 0.18033688011112042f

typedef _Float16 f16x2 __attribute__((ext_vector_type(2)));
typedef _Float16 f16x4 __attribute__((ext_vector_type(4)));
typedef _Float16 f16x8 __attribute__((ext_vector_type(8)));
typedef float    f32x4 __attribute__((ext_vector_type(4)));

#define GLL16(gp, lp) __builtin_amdgcn_global_load_lds(                        \
    (const __attribute__((address_space(1))) void*)(gp),                       \
    (__attribute__((address_space(3))) void*)(lp), 16, 0, 0)

static __device__ __forceinline__ float fast_exp2(float x) {
    float r;
    asm("v_exp_f32 %0, %1" : "=v"(r) : "v"(x));
    return r;
}
static __device__ __forceinline__ f16x2 cvt_pk(float a, float b) {
    f16x2 r;
    asm("v_cvt_pkrtz_f16_f32 %0, %1, %2" : "=v"(r) : "v"(a), "v"(b));
    return r;
}

// ---------------------------------------------------------------------------
// Fused fp32 -> fp16 convert of q,k,v (4M each) + Wq,Wk,Wv,Wo (1M each).
// Wq is additionally scaled by QFOLD (softmax scale folded into Q projection).
// ---------------------------------------------------------------------------
__global__ __launch_bounds__(256) void cvt_all(
    const float* __restrict__ q,  const float* __restrict__ k,
    const float* __restrict__ v,  const float* __restrict__ wq,
    const float* __restrict__ wk, const float* __restrict__ wv,
    const float* __restrict__ wo,
    _Float16* __restrict__ qh,  _Float16* __restrict__ kh,
    _Float16* __restrict__ vh,  _Float16* __restrict__ wqh,
    _Float16* __restrict__ wkh, _Float16* __restrict__ wvh,
    _Float16* __restrict__ woh)
{
    const unsigned u  = blockIdx.x * 256u + threadIdx.x;  // float4 units
    const unsigned U1 = 1u << 20;
    const unsigned U2 = 1u << 18;
    const float* src; _Float16* dst; unsigned off;
    float sc = 1.0f;
    if (u < 3u * U1) {
        const unsigned t = u >> 20; off = u & (U1 - 1u);
        src = (t == 0) ? q  : (t == 1) ? k  : v;
        dst = (t == 0) ? qh : (t == 1) ? kh : vh;
    } else {
        const unsigned r = u - 3u * U1;
        const unsigned t = r >> 18; off = r & (U2 - 1u);
        src = (t == 0) ? wq  : (t == 1) ? wk  : (t == 2) ? wv  : wo;
        dst = (t == 0) ? wqh : (t == 1) ? wkh : (t == 2) ? wvh : woh;
        if (t == 0) sc = QFOLD;
    }
    const float4 x = ((const float4*)src)[off];
    f16x4 y;
    y[0] = (_Float16)(x.x * sc); y[1] = (_Float16)(x.y * sc);
    y[2] = (_Float16)(x.z * sc); y[3] = (_Float16)(x.w * sc);
    ((f16x4*)dst)[off] = y;
}

// ---------------------------------------------------------------------------
// Pack mask [B,1,S,S] int32 -> 1 bit per key.
// ---------------------------------------------------------------------------
__global__ __launch_bounds__(256) void mask_bits(
    const int* __restrict__ mask, unsigned short* __restrict__ bm16)
{
    const size_t t = (size_t)blockIdx.x * 256 + threadIdx.x;
    const int4* p = (const int4*)(mask + t * 16);
    const int4 a = p[0], b = p[1], c = p[2], d = p[3];
    unsigned v = 0;
    v |= (a.x != 0) << 0;  v |= (a.y != 0) << 1;
    v |= (a.z != 0) << 2;  v |= (a.w != 0) << 3;
    v |= (b.x != 0) << 4;  v |= (b.y != 0) << 5;
    v |= (b.z != 0) << 6;  v |= (b.w != 0) << 7;
    v |= (c.x != 0) << 8;  v |= (c.y != 0) << 9;
    v |= (c.z != 0) << 10; v |= (c.w != 0) << 11;
    v |= (d.x != 0) << 12; v |= (d.y != 0) << 13;
    v |= (d.z != 0) << 14; v |= (d.w != 0) << 15;
    bm16[t] = (unsigned short)v;
}

// ---------------------------------------------------------------------------
// MFMA GEMM: Y = X @ W^T + bias*bscale.  X[M,K] fp16, W[N,K] fp16, fp32 acc.
// LAYOUT 0: fp32 Y[m*DD+n]
// LAYOUT 1: fp16 split-head [B,H,S,HD]
// LAYOUT 2: fp16 transposed  [B,H,HD,S]
// ---------------------------------------------------------------------------
template <int LAYOUT>
__global__ __launch_bounds__(256) void gemm_mfma(
    const _Float16* __restrict__ X, const _Float16* __restrict__ W,
    const float* __restrict__ bias, void* __restrict__ Yout, float bscale)
{
    __shared__ _Float16 As[128 * 32];   // 8 KB
    __shared__ _Float16 Bs[64 * 32];    // 4 KB

    const int tid  = threadIdx.x;
    const int lane = tid & 63;
    const int lr   = lane & 15;
    const int lg   = lane >> 4;
    const int wave = tid >> 6;
    const int wr   = wave >> 1;
    const int wc   = wave & 1;

    const int m0 = blockIdx.y << 7;
    const int n0 = blockIdx.x << 6;

    const char* Xb = (const char*)X;
    const char* Wb = (const char*)W;

    const int pa0 = tid * 16;
    const int pa1 = pa0 + 4096;
    const int ra0 = pa0 >> 6, ca0 = pa0 & 63;
    const int ra1 = pa1 >> 6, ca1 = pa1 & 63;
    const int rb0 = pa0 >> 6, cb0 = pa0 & 63;

    f32x4 acc[4][2] = {};

    for (int k0 = 0; k0 < KK; k0 += 32) {
        GLL16(Xb + ((size_t)(m0 + ra0) * KK + k0) * 2 + ca0, (char*)As + pa0);
        GLL16(Xb + ((size_t)(m0 + ra1) * KK + k0) * 2 + ca1, (char*)As + pa1);
        GLL16(Wb + ((size_t)(n0 + rb0) * KK + k0) * 2 + cb0, (char*)Bs + pa0);
        __syncthreads();

        f16x8 af[4], bf[2];
        #pragma unroll
        for (int mi = 0; mi < 4; ++mi)
            af[mi] = *(const f16x8*)((const char*)As +
                       ((wr * 64 + mi * 16 + lr) * 64 + lg * 16));
        #pragma unroll
        for (int ni = 0; ni < 2; ++ni)
            bf[ni] = *(const f16x8*)((const char*)Bs +
                       ((wc * 32 + ni * 16 + lr) * 64 + lg * 16));

        #pragma unroll
        for (int mi = 0; mi < 4; ++mi)
            #pragma unroll
            for (int ni = 0; ni < 2; ++ni)
                acc[mi][ni] = __builtin_amdgcn_mfma_f32_16x16x32_f16(
                    af[mi], bf[ni], acc[mi][ni], 0, 0, 0);
        __syncthreads();
    }

    #pragma unroll
    for (int ni = 0; ni < 2; ++ni) {
        const int n  = n0 + wc * 32 + ni * 16 + lr;
        const float bv = bias[n] * bscale;
        #pragma unroll
        for (int mi = 0; mi < 4; ++mi) {
            const int mbase = m0 + wr * 64 + mi * 16 + lg * 4;
            if (LAYOUT == 0) {
                #pragma unroll
                for (int r = 0; r < 4; ++r)
                    ((float*)Yout)[(size_t)(mbase + r) * DD + n] =
                        acc[mi][ni][r] + bv;
            } else if (LAYOUT == 1) {
                #pragma unroll
                for (int r = 0; r < 4; ++r) {
                    const int m = mbase + r;
                    const int b_ = m >> 11, s_ = m & (SS - 1);
                    const int h_ = n >> 6,  d_ = n & (HDIM - 1);
                    ((_Float16*)Yout)[(((size_t)(b_ * HH + h_)) * SS + s_) * HDIM + d_] =
                        (_Float16)(acc[mi][ni][r] + bv);
                }
            } else {
                const int b_ = mbase >> 11, s_ = mbase & (SS - 1);
                const int h_ = n >> 6,      d_ = n & (HDIM - 1);
                f16x4 tv;
                #pragma unroll
                for (int r = 0; r < 4; ++r) tv[r] = (_Float16)(acc[mi][ni][r] + bv);
                *(f16x4*)((_Float16*)Yout +
                          (((size_t)(b_ * HH + h_)) * HDIM + d_) * SS + s_) = tv;
            }
        }
    }
}

// ---------------------------------------------------------------------------
// MFMA fp16 flash attention, v3.
// Scores arrive pre-scaled in exp2 domain (QFOLD folded into Q projection).
// l computed by ones-row MFMA; defer-max (THR=8); pkrtz packing; raw v_exp.
// ---------------------------------------------------------------------------
__global__ __launch_bounds__(256) void attn_mfma3(
    const _Float16* __restrict__ Qh, const _Float16* __restrict__ Kh,
    const _Float16* __restrict__ Vt, const unsigned long long* __restrict__ bm,
    _Float16* __restrict__ AO)
{
    __shared__ _Float16 KbufS[2][4096];   // [key][64d], rows 128B, swizzled
    __shared__ _Float16 VbufS[2][4096];   // [d][64key], rows 128B, swizzled

    const int tid  = threadIdx.x;
    const int lane = tid & 63;
    const int wq   = tid >> 6;
    const int bh   = blockIdx.y;
    const int b_   = bh >> 4;
    const int h_   = bh & (HH - 1);
    const int q0   = blockIdx.x << 6;
    const int lr   = lane & 15;
    const int lg   = lane >> 4;

    const int qrow = q0 + wq * 16 + lr;
    const _Float16* qbase = Qh + ((size_t)bh * SS + qrow) * HDIM;
    const f16x8 qf0 = *(const f16x8*)(qbase + lg * 8);
    const f16x8 qf1 = *(const f16x8*)(qbase + 32 + lg * 8);

    const int c0 = tid, c1 = tid + 256;
    const int kr0 = c0 >> 3, krc0 = (c0 & 7) ^ (kr0 & 7);
    const int kr1 = c1 >> 3, krc1 = (c1 & 7) ^ (kr1 & 7);
    const _Float16* gK0 = Kh + ((size_t)bh * SS + kr0) * HDIM + krc0 * 8;
    const _Float16* gK1 = Kh + ((size_t)bh * SS + kr1) * HDIM + krc1 * 8;
    const _Float16* gV0 = Vt + ((size_t)bh * HDIM + kr0) * SS + krc0 * 8;
    const _Float16* gV1 = Vt + ((size_t)bh * HDIM + kr1) * SS + krc1 * 8;
    const int woff = (tid >> 6) << 10;

    float m_run = -INFINITY;
    f32x4 oacc[4];
    #pragma unroll
    for (int dc = 0; dc < 4; ++dc) oacc[dc] = (f32x4){0.f, 0.f, 0.f, 0.f};
    f32x4 lacc = (f32x4){0.f, 0.f, 0.f, 0.f};

    f16x8 ones;
    #pragma unroll
    for (int e = 0; e < 8; ++e) ones[e] = (_Float16)1.0f;

    const unsigned long long* bmrow = bm + ((size_t)b_ * SS + qrow) * (SS / 64);

#define STAGE(KT, BSEL) do {                                                   \
    GLL16(gK0 + (size_t)(KT) * HDIM, (char*)KbufS[BSEL] + woff);               \
    GLL16(gK1 + (size_t)(KT) * HDIM, (char*)KbufS[BSEL] + 4096 + woff);        \
    GLL16(gV0 + (KT), (char*)VbufS[BSEL] + woff);                              \
    GLL16(gV1 + (KT), (char*)VbufS[BSEL] + 4096 + woff);                       \
  } while (0)

    STAGE(0, 0);
    __syncthreads();

    const int xk0 = ((lg       ^ (lr & 7)) << 4);
    const int xk1 = (((4 + lg) ^ (lr & 7)) << 4);
    const int xv  = ((lr & 7) << 4);

    unsigned long long bmv = bmrow[0];

    for (int t = 0; t < SS / 64; ++t) {
        const int cur = t & 1;
        if (t < SS / 64 - 1) STAGE((t + 1) * 64, cur ^ 1);
        unsigned long long bmv_next = 0;
        if (t < SS / 64 - 1) bmv_next = bmrow[t + 1];

        const char* kb = (const char*)KbufS[cur];
        const char* vb = (const char*)VbufS[cur];

        // ---- QK^T (pre-scaled -> exp2 domain) ----
        f32x4 sarr[4];
        __builtin_amdgcn_s_setprio(1);
        #pragma unroll
        for (int kg = 0; kg < 4; ++kg) {
            const char* rp = kb + (kg * 16 + lr) * 128;
            const f16x8 kf0 = *(const f16x8*)(rp + xk0);
            const f16x8 kf1 = *(const f16x8*)(rp + xk1);
            f32x4 a = (f32x4){0.f, 0.f, 0.f, 0.f};
            a = __builtin_amdgcn_mfma_f32_16x16x32_f16(kf0, qf0, a, 0, 0, 0);
            a = __builtin_amdgcn_mfma_f32_16x16x32_f16(kf1, qf1, a, 0, 0, 0);
            sarr[kg] = a;
        }
        __builtin_amdgcn_s_setprio(0);

        float sv[16];
        #pragma unroll
        for (int kg = 0; kg < 4; ++kg)
            #pragma unroll
            for (int r = 0; r < 4; ++r)
                sv[kg * 4 + r] = sarr[kg][r];

        if (~bmv) {   // any masked key (not taken for all-ones mask)
            #pragma unroll
            for (int kg = 0; kg < 4; ++kg)
                #pragma unroll
                for (int r = 0; r < 4; ++r)
                    if (!((bmv >> (kg * 16 + lg * 4 + r)) & 1ull))
                        sv[kg * 4 + r] = -1e9f;
        }
        bmv = bmv_next;

        // ---- defer-max online softmax ----
        float pmax = sv[0];
        #pragma unroll
        for (int i = 1; i < 16; ++i) pmax = fmaxf(pmax, sv[i]);
        pmax = fmaxf(pmax, __shfl_xor(pmax, 16));
        pmax = fmaxf(pmax, __shfl_xor(pmax, 32));

        if (!__all(pmax <= m_run + 8.0f)) {
            const float m_new = fmaxf(m_run, pmax);
            const float corr  = fast_exp2(m_run - m_new);  // -inf -> 0
            #pragma unroll
            for (int dc = 0; dc < 4; ++dc) oacc[dc] *= corr;
            lacc *= corr;
            m_run = m_new;
        }

        float p[16];
        #pragma unroll
        for (int i = 0; i < 16; ++i) p[i] = fast_exp2(sv[i] - m_run);

        union { f16x2 h2[4]; f16x8 v8; } u0, u1;
        #pragma unroll
        for (int e = 0; e < 4; ++e) {
            u0.h2[e] = cvt_pk(p[2 * e],     p[2 * e + 1]);
            u1.h2[e] = cvt_pk(p[8 + 2 * e], p[9 + 2 * e]);
        }
        const f16x8 pb0 = u0.v8, pb1 = u1.v8;

        // ---- PV + ones-row l accumulation ----
        __builtin_amdgcn_s_setprio(1);
        #pragma unroll
        for (int dc = 0; dc < 4; ++dc) {
            const char* rp = vb + (dc * 16 + lr) * 128;
            const f16x4 a0 = *(const f16x4*)(rp + ((0  + lg * 8) ^ xv));
            const f16x4 a1 = *(const f16x4*)(rp + ((32 + lg * 8) ^ xv));
            const f16x4 a2 = *(const f16x4*)(rp + ((64 + lg * 8) ^ xv));
            const f16x4 a3 = *(const f16x4*)(rp + ((96 + lg * 8) ^ xv));
            const f16x8 va0 = __builtin_shufflevector(a0, a1, 0, 1, 2, 3, 4, 5, 6, 7);
            const f16x8 va1 = __builtin_shufflevector(a2, a3, 0, 1, 2, 3, 4, 5, 6, 7);
            oacc[dc] = __builtin_amdgcn_mfma_f32_16x16x32_f16(va0, pb0, oacc[dc], 0, 0, 0);
            oacc[dc] = __builtin_amdgcn_mfma_f32_16x16x32_f16(va1, pb1, oacc[dc], 0, 0, 0);
        }
        lacc = __builtin_amdgcn_mfma_f32_16x16x32_f16(ones, pb0, lacc, 0, 0, 0);
        lacc = __builtin_amdgcn_mfma_f32_16x16x32_f16(ones, pb1, lacc, 0, 0, 0);
        __builtin_amdgcn_s_setprio(0);
        __syncthreads();
    }
#undef STAGE

    const float invl = 1.0f / lacc[0];
    _Float16* obase = AO + ((size_t)b_ * SS + qrow) * DD + h_ * HDIM;
    #pragma unroll
    for (int dc = 0; dc < 4; ++dc) {
        f16x4 r;
        r[0] = (_Float16)(oacc[dc][0] * invl);
        r[1] = (_Float16)(oacc[dc][1] * invl);
        r[2] = (_Float16)(oacc[dc][2] * invl);
        r[3] = (_Float16)(oacc[dc][3] * invl);
        *reinterpret_cast<f16x4*>(obase + dc * 16 + lg * 4) = r;
    }
}

// ---------------------------------------------------------------------------
extern "C" void kernel_launch(void* const* d_in, const int* in_sizes, int n_in,
                              void* d_out, int out_size, void* d_ws, size_t ws_size,
                              hipStream_t stream)
{
    const float* q    = (const float*)d_in[0];
    const float* k    = (const float*)d_in[1];
    const float* v    = (const float*)d_in[2];
    const int*   mask = (const int*)d_in[3];
    const float* Wq   = (const float*)d_in[4];
    const float* bq   = (const float*)d_in[5];
    const float* Wk   = (const float*)d_in[6];
    const float* bk   = (const float*)d_in[7];
    const float* Wv   = (const float*)d_in[8];
    const float* bv   = (const float*)d_in[9];
    const float* Wo   = (const float*)d_in[10];
    const float* bo   = (const float*)d_in[11];
    float* out = (float*)d_out;

    char* w = (char*)d_ws;
    _Float16* qx  = (_Float16*)(w);                       // 8 MB (dead after Q-GEMM)
    _Float16* kx  = (_Float16*)(w + 8  * 1048576);
    _Float16* vx  = (_Float16*)(w + 16 * 1048576);
    _Float16* wqh = (_Float16*)(w + 24 * 1048576);        // 2 MB each
    _Float16* wkh = (_Float16*)(w + 26 * 1048576);
    _Float16* wvh = (_Float16*)(w + 28 * 1048576);
    _Float16* woh = (_Float16*)(w + 30 * 1048576);
    _Float16* Qh  = (_Float16*)(w + 32 * 1048576);        // 8 MB each
    _Float16* Kh  = (_Float16*)(w + 40 * 1048576);
    _Float16* Vt  = (_Float16*)(w + 48 * 1048576);        // [B,H,HD,S]
    _Float16* AO  = (_Float16*)(w + 56 * 1048576);        // 8 MB
    unsigned long long* bm = (unsigned long long*)(w);    // 1 MB, reuses qx

    cvt_all<<<16384, 256, 0, stream>>>(q, k, v, Wq, Wk, Wv, Wo,
                                       qx, kx, vx, wqh, wkh, wvh, woh);

    const dim3 gblk(DD / 64, MM / 128);          // (16, 32) = 512 blocks
    gemm_mfma<1><<<gblk, 256, 0, stream>>>(qx, wqh, bq, Qh, QFOLD);
    gemm_mfma<1><<<gblk, 256, 0, stream>>>(kx, wkh, bk, Kh, 1.0f);
    gemm_mfma<2><<<gblk, 256, 0, stream>>>(vx, wvh, bv, Vt, 1.0f);

    // qx is dead now; pack mask bits into its region.
    mask_bits<<<2048, 256, 0, stream>>>(mask, (unsigned short*)bm);

    const dim3 gattn(SS / 64, BB * HH);          // (32, 32)
    attn_mfma3<<<gattn, 256, 0, stream>>>(Qh, Kh, Vt, bm, AO);

    gemm_mfma<0><<<gblk, 256, 0, stream>>>(AO, woh, bo, out, 1.0f);
}

// Round 7
// 167.582 us; speedup vs baseline: 13.9617x; 1.1837x over previous
//
#include <hip/hip_runtime.h>
#include <math.h>

#define BB 2
#define SS 2048
#define DD 1024
#define HH 16
#define HDIM 64
#define KK 1024           // GEMM K  (= D)
#define MM 4096           // GEMM M  (= B*S)

// 0.125 (1/sqrt(HD)) * log2(e): folds softmax scale+base-change into Wq/bq.
#define QFOLD 0.18033688011112042f

typedef _Float16 f16x2 __attribute__((ext_vector_type(2)));
typedef _Float16 f16x4 __attribute__((ext_vector_type(4)));
typedef _Float16 f16x8 __attribute__((ext_vector_type(8)));
typedef float    f32x4 __attribute__((ext_vector_type(4)));

#define GLL16(gp, lp) __builtin_amdgcn_global_load_lds(                        \
    (const __attribute__((address_space(1))) void*)(gp),                       \
    (__attribute__((address_space(3))) void*)(lp), 16, 0, 0)

static __device__ __forceinline__ float fast_exp2(float x) {
    float r;
    asm("v_exp_f32 %0, %1" : "=v"(r) : "v"(x));
    return r;
}
static __device__ __forceinline__ f16x2 cvt_pk(float a, float b) {
    f16x2 r;
    asm("v_cvt_pkrtz_f16_f32 %0, %1, %2" : "=v"(r) : "v"(a), "v"(b));
    return r;
}

// ---------------------------------------------------------------------------
// prep: blocks [0,16384): fp32->fp16 convert of q,k,v + Wq,Wk,Wv,Wo
//       blocks [16384,18432): mask int32 -> 1 bit per key
// WORKSPACE MAP (57 MB of d_ws):
//   [ 0, 8)MB  qx   (prep->qkv)   then AO (attn->out)  -- qx dead before attn
//   [ 8,16)MB  kx        [16,24)MB vx
//   [24,32)MB  wqh,wkh,wvh,woh (2MB each)
//   [32,40)MB  Qh   [40,48)MB Kh   [48,56)MB Vt
//   [56,57)MB  bm   (prep->attn; touched by nothing else)
// ---------------------------------------------------------------------------
__global__ __launch_bounds__(256) void prep(
    const float* __restrict__ q,  const float* __restrict__ k,
    const float* __restrict__ v,  const float* __restrict__ wq,
    const float* __restrict__ wk, const float* __restrict__ wv,
    const float* __restrict__ wo, const int* __restrict__ mask,
    _Float16* __restrict__ qh,  _Float16* __restrict__ kh,
    _Float16* __restrict__ vh,  _Float16* __restrict__ wqh,
    _Float16* __restrict__ wkh, _Float16* __restrict__ wvh,
    _Float16* __restrict__ woh, unsigned short* __restrict__ bm16)
{
    if (blockIdx.x < 16384u) {
        const unsigned u  = blockIdx.x * 256u + threadIdx.x;  // float4 units
        const unsigned U1 = 1u << 20;
        const unsigned U2 = 1u << 18;
        const float* src; _Float16* dst; unsigned off;
        float sc = 1.0f;
        if (u < 3u * U1) {
            const unsigned t = u >> 20; off = u & (U1 - 1u);
            src = (t == 0) ? q  : (t == 1) ? k  : v;
            dst = (t == 0) ? qh : (t == 1) ? kh : vh;
        } else {
            const unsigned r = u - 3u * U1;
            const unsigned t = r >> 18; off = r & (U2 - 1u);
            src = (t == 0) ? wq  : (t == 1) ? wk  : (t == 2) ? wv  : wo;
            dst = (t == 0) ? wqh : (t == 1) ? wkh : (t == 2) ? wvh : woh;
            if (t == 0) sc = QFOLD;
        }
        const float4 x = ((const float4*)src)[off];
        f16x4 y;
        y[0] = (_Float16)(x.x * sc); y[1] = (_Float16)(x.y * sc);
        y[2] = (_Float16)(x.z * sc); y[3] = (_Float16)(x.w * sc);
        ((f16x4*)dst)[off] = y;
    } else {
        const size_t t = (size_t)(blockIdx.x - 16384u) * 256 + threadIdx.x;
        const int4* p = (const int4*)(mask + t * 16);
        const int4 a = p[0], b = p[1], c = p[2], d = p[3];
        unsigned vv = 0;
        vv |= (a.x != 0) << 0;  vv |= (a.y != 0) << 1;
        vv |= (a.z != 0) << 2;  vv |= (a.w != 0) << 3;
        vv |= (b.x != 0) << 4;  vv |= (b.y != 0) << 5;
        vv |= (b.z != 0) << 6;  vv |= (b.w != 0) << 7;
        vv |= (c.x != 0) << 8;  vv |= (c.y != 0) << 9;
        vv |= (c.z != 0) << 10; vv |= (c.w != 0) << 11;
        vv |= (d.x != 0) << 12; vv |= (d.y != 0) << 13;
        vv |= (d.z != 0) << 14; vv |= (d.w != 0) << 15;
        bm16[t] = (unsigned short)vv;
    }
}

// ---------------------------------------------------------------------------
// Shared MFMA-GEMM body (tile 128x64, BK=32, 4 waves 2x2).
// ---------------------------------------------------------------------------
#define GEMM_BODY(X, W)                                                        \
    __shared__ _Float16 As[128 * 32];                                          \
    __shared__ _Float16 Bs[64 * 32];                                           \
    const int tid  = threadIdx.x;                                              \
    const int lane = tid & 63;                                                 \
    const int lr   = lane & 15;                                                \
    const int lg   = lane >> 4;                                                \
    const int wave = tid >> 6;                                                 \
    const int wr   = wave >> 1;                                                \
    const int wc   = wave & 1;                                                 \
    const int m0 = blockIdx.y << 7;                                            \
    const int n0 = blockIdx.x << 6;                                            \
    const char* Xb = (const char*)(X);                                         \
    const char* Wb = (const char*)(W);                                         \
    const int pa0 = tid * 16;                                                  \
    const int pa1 = pa0 + 4096;                                                \
    const int ra0 = pa0 >> 6, ca0 = pa0 & 63;                                  \
    const int ra1 = pa1 >> 6, ca1 = pa1 & 63;                                  \
    const int rb0 = pa0 >> 6, cb0 = pa0 & 63;                                  \
    f32x4 acc[4][2] = {};                                                      \
    for (int k0 = 0; k0 < KK; k0 += 32) {                                      \
        GLL16(Xb + ((size_t)(m0 + ra0) * KK + k0) * 2 + ca0, (char*)As + pa0); \
        GLL16(Xb + ((size_t)(m0 + ra1) * KK + k0) * 2 + ca1, (char*)As + pa1); \
        GLL16(Wb + ((size_t)(n0 + rb0) * KK + k0) * 2 + cb0, (char*)Bs + pa0); \
        __syncthreads();                                                       \
        f16x8 af[4], bf[2];                                                    \
        _Pragma("unroll")                                                      \
        for (int mi = 0; mi < 4; ++mi)                                         \
            af[mi] = *(const f16x8*)((const char*)As +                         \
                       ((wr * 64 + mi * 16 + lr) * 64 + lg * 16));             \
        _Pragma("unroll")                                                      \
        for (int ni = 0; ni < 2; ++ni)                                         \
            bf[ni] = *(const f16x8*)((const char*)Bs +                         \
                       ((wc * 32 + ni * 16 + lr) * 64 + lg * 16));             \
        _Pragma("unroll")                                                      \
        for (int mi = 0; mi < 4; ++mi)                                         \
            _Pragma("unroll")                                                  \
            for (int ni = 0; ni < 2; ++ni)                                     \
                acc[mi][ni] = __builtin_amdgcn_mfma_f32_16x16x32_f16(          \
                    af[mi], bf[ni], acc[mi][ni], 0, 0, 0);                     \
        __syncthreads();                                                       \
    }

// ---------------------------------------------------------------------------
// Fused QKV projection: grid.z selects (q,k,v).  z<2 -> split-head fp16;
// z==2 -> transposed [B,H,HD,S] fp16 (V).
// ---------------------------------------------------------------------------
__global__ __launch_bounds__(256) void gemm_qkv(
    const _Float16* __restrict__ qx, const _Float16* __restrict__ kx,
    const _Float16* __restrict__ vx,
    const _Float16* __restrict__ wqh, const _Float16* __restrict__ wkh,
    const _Float16* __restrict__ wvh,
    const float* __restrict__ bq, const float* __restrict__ bk,
    const float* __restrict__ bv,
    _Float16* __restrict__ Qh, _Float16* __restrict__ Kh,
    _Float16* __restrict__ Vt)
{
    const int z = blockIdx.z;
    const _Float16* X = (z == 0) ? qx : (z == 1) ? kx : vx;
    const _Float16* W = (z == 0) ? wqh : (z == 1) ? wkh : wvh;
    const float* bias = (z == 0) ? bq : (z == 1) ? bk : bv;
    const float bsc   = (z == 0) ? QFOLD : 1.0f;
    _Float16* Yh      = (z == 0) ? Qh : Kh;

    GEMM_BODY(X, W)

    #pragma unroll
    for (int ni = 0; ni < 2; ++ni) {
        const int n  = n0 + wc * 32 + ni * 16 + lr;
        const float bv_ = bias[n] * bsc;
        #pragma unroll
        for (int mi = 0; mi < 4; ++mi) {
            const int mbase = m0 + wr * 64 + mi * 16 + lg * 4;
            if (z < 2) {
                #pragma unroll
                for (int r = 0; r < 4; ++r) {
                    const int m = mbase + r;
                    const int b_ = m >> 11, s_ = m & (SS - 1);
                    const int h_ = n >> 6,  d_ = n & (HDIM - 1);
                    Yh[(((size_t)(b_ * HH + h_)) * SS + s_) * HDIM + d_] =
                        (_Float16)(acc[mi][ni][r] + bv_);
                }
            } else {
                const int b_ = mbase >> 11, s_ = mbase & (SS - 1);
                const int h_ = n >> 6,      d_ = n & (HDIM - 1);
                f16x4 tv;
                #pragma unroll
                for (int r = 0; r < 4; ++r) tv[r] = (_Float16)(acc[mi][ni][r] + bv_);
                *(f16x4*)(Vt + (((size_t)(b_ * HH + h_)) * HDIM + d_) * SS + s_) = tv;
            }
        }
    }
}

// ---------------------------------------------------------------------------
// Output projection: fp32 Y[m*DD+n].
// ---------------------------------------------------------------------------
__global__ __launch_bounds__(256) void gemm_out(
    const _Float16* __restrict__ X, const _Float16* __restrict__ W,
    const float* __restrict__ bias, float* __restrict__ Y)
{
    GEMM_BODY(X, W)

    #pragma unroll
    for (int ni = 0; ni < 2; ++ni) {
        const int n  = n0 + wc * 32 + ni * 16 + lr;
        const float bv_ = bias[n];
        #pragma unroll
        for (int mi = 0; mi < 4; ++mi) {
            const int mbase = m0 + wr * 64 + mi * 16 + lg * 4;
            #pragma unroll
            for (int r = 0; r < 4; ++r)
                Y[(size_t)(mbase + r) * DD + n] = acc[mi][ni][r] + bv_;
        }
    }
}

// ---------------------------------------------------------------------------
// MFMA fp16 flash attention, v4: 32 q-rows per wave (two chains A/B),
// 128 q-rows per block, grid (BH, S/128) so same-bh blocks share an XCD.
// K/V staged via global_load_lds into XOR-swizzled LDS, double-buffered.
// ---------------------------------------------------------------------------
__global__ __launch_bounds__(256) void attn_mfma4(
    const _Float16* __restrict__ Qh, const _Float16* __restrict__ Kh,
    const _Float16* __restrict__ Vt, const unsigned long long* __restrict__ bm,
    _Float16* __restrict__ AO)
{
    __shared__ _Float16 KbufS[2][4096];   // [key][64d], rows 128B, swizzled
    __shared__ _Float16 VbufS[2][4096];   // [d][64key], rows 128B, swizzled

    const int tid  = threadIdx.x;
    const int lane = tid & 63;
    const int wq   = tid >> 6;
    const int bh   = blockIdx.x;           // bh fastest -> same-XCD K/V reuse
    const int b_   = bh >> 4;
    const int h_   = bh & (HH - 1);
    const int q0   = blockIdx.y << 7;      // 128 q rows / block
    const int lr   = lane & 15;
    const int lg   = lane >> 4;

    const int qrowA = q0 + wq * 32 + lr;
    const int qrowB = qrowA + 16;
    const _Float16* qbA = Qh + ((size_t)bh * SS + qrowA) * HDIM;
    const _Float16* qbB = Qh + ((size_t)bh * SS + qrowB) * HDIM;
    const f16x8 qfA0 = *(const f16x8*)(qbA + lg * 8);
    const f16x8 qfA1 = *(const f16x8*)(qbA + 32 + lg * 8);
    const f16x8 qfB0 = *(const f16x8*)(qbB + lg * 8);
    const f16x8 qfB1 = *(const f16x8*)(qbB + 32 + lg * 8);

    const int c0 = tid, c1 = tid + 256;
    const int kr0 = c0 >> 3, krc0 = (c0 & 7) ^ (kr0 & 7);
    const int kr1 = c1 >> 3, krc1 = (c1 & 7) ^ (kr1 & 7);
    const _Float16* gK0 = Kh + ((size_t)bh * SS + kr0) * HDIM + krc0 * 8;
    const _Float16* gK1 = Kh + ((size_t)bh * SS + kr1) * HDIM + krc1 * 8;
    const _Float16* gV0 = Vt + ((size_t)bh * HDIM + kr0) * SS + krc0 * 8;
    const _Float16* gV1 = Vt + ((size_t)bh * HDIM + kr1) * SS + krc1 * 8;
    const int woff = (tid >> 6) << 10;

    float mA = -INFINITY, mB = -INFINITY;
    f32x4 oaccA[4], oaccB[4];
    #pragma unroll
    for (int dc = 0; dc < 4; ++dc) {
        oaccA[dc] = (f32x4){0.f, 0.f, 0.f, 0.f};
        oaccB[dc] = (f32x4){0.f, 0.f, 0.f, 0.f};
    }
    f32x4 laccA = (f32x4){0.f, 0.f, 0.f, 0.f};
    f32x4 laccB = (f32x4){0.f, 0.f, 0.f, 0.f};

    f16x8 ones;
    #pragma unroll
    for (int e = 0; e < 8; ++e) ones[e] = (_Float16)1.0f;

    const unsigned long long* bmrowA = bm + ((size_t)b_ * SS + qrowA) * (SS / 64);
    const unsigned long long* bmrowB = bm + ((size_t)b_ * SS + qrowB) * (SS / 64);

#define STAGE(KT, BSEL) do {                                                   \
    GLL16(gK0 + (size_t)(KT) * HDIM, (char*)KbufS[BSEL] + woff);               \
    GLL16(gK1 + (size_t)(KT) * HDIM, (char*)KbufS[BSEL] + 4096 + woff);        \
    GLL16(gV0 + (KT), (char*)VbufS[BSEL] + woff);                              \
    GLL16(gV1 + (KT), (char*)VbufS[BSEL] + 4096 + woff);                       \
  } while (0)

    STAGE(0, 0);
    __syncthreads();

    const int xk0 = ((lg       ^ (lr & 7)) << 4);
    const int xk1 = (((4 + lg) ^ (lr & 7)) << 4);
    const int xv  = ((lr & 7) << 4);

    unsigned long long bmA = bmrowA[0];
    unsigned long long bmB = bmrowB[0];

    for (int t = 0; t < SS / 64; ++t) {
        const int cur = t & 1;
        if (t < SS / 64 - 1) STAGE((t + 1) * 64, cur ^ 1);
        unsigned long long bmA_n = 0, bmB_n = 0;
        if (t < SS / 64 - 1) { bmA_n = bmrowA[t + 1]; bmB_n = bmrowB[t + 1]; }

        const char* kb = (const char*)KbufS[cur];
        const char* vb = (const char*)VbufS[cur];

        // ---- QK^T for both chains (shared K fragments) ----
        f32x4 sA[4], sB[4];
        __builtin_amdgcn_s_setprio(1);
        #pragma unroll
        for (int kg = 0; kg < 4; ++kg) {
            const char* rp = kb + (kg * 16 + lr) * 128;
            const f16x8 kf0 = *(const f16x8*)(rp + xk0);
            const f16x8 kf1 = *(const f16x8*)(rp + xk1);
            f32x4 a = (f32x4){0.f, 0.f, 0.f, 0.f};
            a = __builtin_amdgcn_mfma_f32_16x16x32_f16(kf0, qfA0, a, 0, 0, 0);
            a = __builtin_amdgcn_mfma_f32_16x16x32_f16(kf1, qfA1, a, 0, 0, 0);
            sA[kg] = a;
            f32x4 b2 = (f32x4){0.f, 0.f, 0.f, 0.f};
            b2 = __builtin_amdgcn_mfma_f32_16x16x32_f16(kf0, qfB0, b2, 0, 0, 0);
            b2 = __builtin_amdgcn_mfma_f32_16x16x32_f16(kf1, qfB1, b2, 0, 0, 0);
            sB[kg] = b2;
        }
        __builtin_amdgcn_s_setprio(0);

        float svA[16], svB[16];
        #pragma unroll
        for (int kg = 0; kg < 4; ++kg)
            #pragma unroll
            for (int r = 0; r < 4; ++r) {
                svA[kg * 4 + r] = sA[kg][r];
                svB[kg * 4 + r] = sB[kg][r];
            }

        if (~bmA) {
            #pragma unroll
            for (int kg = 0; kg < 4; ++kg)
                #pragma unroll
                for (int r = 0; r < 4; ++r)
                    if (!((bmA >> (kg * 16 + lg * 4 + r)) & 1ull))
                        svA[kg * 4 + r] = -1e9f;
        }
        if (~bmB) {
            #pragma unroll
            for (int kg = 0; kg < 4; ++kg)
                #pragma unroll
                for (int r = 0; r < 4; ++r)
                    if (!((bmB >> (kg * 16 + lg * 4 + r)) & 1ull))
                        svB[kg * 4 + r] = -1e9f;
        }
        bmA = bmA_n; bmB = bmB_n;

        // ---- defer-max online softmax, both chains ----
        float pmA = svA[0], pmB = svB[0];
        #pragma unroll
        for (int i = 1; i < 16; ++i) {
            pmA = fmaxf(pmA, svA[i]);
            pmB = fmaxf(pmB, svB[i]);
        }
        pmA = fmaxf(pmA, __shfl_xor(pmA, 16));
        pmA = fmaxf(pmA, __shfl_xor(pmA, 32));
        pmB = fmaxf(pmB, __shfl_xor(pmB, 16));
        pmB = fmaxf(pmB, __shfl_xor(pmB, 32));

        if (!__all(pmA <= mA + 8.0f)) {
            const float m_new = fmaxf(mA, pmA);
            const float corr  = fast_exp2(mA - m_new);
            #pragma unroll
            for (int dc = 0; dc < 4; ++dc) oaccA[dc] *= corr;
            laccA *= corr;
            mA = m_new;
        }
        if (!__all(pmB <= mB + 8.0f)) {
            const float m_new = fmaxf(mB, pmB);
            const float corr  = fast_exp2(mB - m_new);
            #pragma unroll
            for (int dc = 0; dc < 4; ++dc) oaccB[dc] *= corr;
            laccB *= corr;
            mB = m_new;
        }

        float pA[16], pB[16];
        #pragma unroll
        for (int i = 0; i < 16; ++i) {
            pA[i] = fast_exp2(svA[i] - mA);
            pB[i] = fast_exp2(svB[i] - mB);
        }

        union { f16x2 h2[4]; f16x8 v8; } uA0, uA1, uB0, uB1;
        #pragma unroll
        for (int e = 0; e < 4; ++e) {
            uA0.h2[e] = cvt_pk(pA[2 * e],     pA[2 * e + 1]);
            uA1.h2[e] = cvt_pk(pA[8 + 2 * e], pA[9 + 2 * e]);
            uB0.h2[e] = cvt_pk(pB[2 * e],     pB[2 * e + 1]);
            uB1.h2[e] = cvt_pk(pB[8 + 2 * e], pB[9 + 2 * e]);
        }
        const f16x8 pbA0 = uA0.v8, pbA1 = uA1.v8;
        const f16x8 pbB0 = uB0.v8, pbB1 = uB1.v8;

        // ---- PV for both chains (shared V fragments) + l rows ----
        __builtin_amdgcn_s_setprio(1);
        #pragma unroll
        for (int dc = 0; dc < 4; ++dc) {
            const char* rp = vb + (dc * 16 + lr) * 128;
            const f16x4 a0 = *(const f16x4*)(rp + ((0  + lg * 8) ^ xv));
            const f16x4 a1 = *(const f16x4*)(rp + ((32 + lg * 8) ^ xv));
            const f16x4 a2 = *(const f16x4*)(rp + ((64 + lg * 8) ^ xv));
            const f16x4 a3 = *(const f16x4*)(rp + ((96 + lg * 8) ^ xv));
            const f16x8 va0 = __builtin_shufflevector(a0, a1, 0, 1, 2, 3, 4, 5, 6, 7);
            const f16x8 va1 = __builtin_shufflevector(a2, a3, 0, 1, 2, 3, 4, 5, 6, 7);
            oaccA[dc] = __builtin_amdgcn_mfma_f32_16x16x32_f16(va0, pbA0, oaccA[dc], 0, 0, 0);
            oaccA[dc] = __builtin_amdgcn_mfma_f32_16x16x32_f16(va1, pbA1, oaccA[dc], 0, 0, 0);
            oaccB[dc] = __builtin_amdgcn_mfma_f32_16x16x32_f16(va0, pbB0, oaccB[dc], 0, 0, 0);
            oaccB[dc] = __builtin_amdgcn_mfma_f32_16x16x32_f16(va1, pbB1, oaccB[dc], 0, 0, 0);
        }
        laccA = __builtin_amdgcn_mfma_f32_16x16x32_f16(ones, pbA0, laccA, 0, 0, 0);
        laccA = __builtin_amdgcn_mfma_f32_16x16x32_f16(ones, pbA1, laccA, 0, 0, 0);
        laccB = __builtin_amdgcn_mfma_f32_16x16x32_f16(ones, pbB0, laccB, 0, 0, 0);
        laccB = __builtin_amdgcn_mfma_f32_16x16x32_f16(ones, pbB1, laccB, 0, 0, 0);
        __builtin_amdgcn_s_setprio(0);
        __syncthreads();
    }
#undef STAGE

    const float invlA = 1.0f / laccA[0];
    const float invlB = 1.0f / laccB[0];
    _Float16* obA = AO + ((size_t)b_ * SS + qrowA) * DD + h_ * HDIM;
    _Float16* obB = AO + ((size_t)b_ * SS + qrowB) * DD + h_ * HDIM;
    #pragma unroll
    for (int dc = 0; dc < 4; ++dc) {
        f16x4 rA, rB;
        #pragma unroll
        for (int r = 0; r < 4; ++r) {
            rA[r] = (_Float16)(oaccA[dc][r] * invlA);
            rB[r] = (_Float16)(oaccB[dc][r] * invlB);
        }
        *reinterpret_cast<f16x4*>(obA + dc * 16 + lg * 4) = rA;
        *reinterpret_cast<f16x4*>(obB + dc * 16 + lg * 4) = rB;
    }
}

// ---------------------------------------------------------------------------
extern "C" void kernel_launch(void* const* d_in, const int* in_sizes, int n_in,
                              void* d_out, int out_size, void* d_ws, size_t ws_size,
                              hipStream_t stream)
{
    const float* q    = (const float*)d_in[0];
    const float* k    = (const float*)d_in[1];
    const float* v    = (const float*)d_in[2];
    const int*   mask = (const int*)d_in[3];
    const float* Wq   = (const float*)d_in[4];
    const float* bq   = (const float*)d_in[5];
    const float* Wk   = (const float*)d_in[6];
    const float* bk   = (const float*)d_in[7];
    const float* Wv   = (const float*)d_in[8];
    const float* bv   = (const float*)d_in[9];
    const float* Wo   = (const float*)d_in[10];
    const float* bo   = (const float*)d_in[11];
    float* out = (float*)d_out;

    char* w = (char*)d_ws;
    _Float16* qx  = (_Float16*)(w);                       // 8 MB (dead after QKV)
    _Float16* kx  = (_Float16*)(w + 8  * 1048576);
    _Float16* vx  = (_Float16*)(w + 16 * 1048576);
    _Float16* wqh = (_Float16*)(w + 24 * 1048576);        // 2 MB each
    _Float16* wkh = (_Float16*)(w + 26 * 1048576);
    _Float16* wvh = (_Float16*)(w + 28 * 1048576);
    _Float16* woh = (_Float16*)(w + 30 * 1048576);
    _Float16* Qh  = (_Float16*)(w + 32 * 1048576);        // 8 MB each
    _Float16* Kh  = (_Float16*)(w + 40 * 1048576);
    _Float16* Vt  = (_Float16*)(w + 48 * 1048576);        // [B,H,HD,S]
    unsigned long long* bm = (unsigned long long*)(w + 56 * 1048576); // 1 MB
    _Float16* AO  = (_Float16*)(w);                       // reuses qx region

    prep<<<18432, 256, 0, stream>>>(q, k, v, Wq, Wk, Wv, Wo, mask,
                                    qx, kx, vx, wqh, wkh, wvh, woh,
                                    (unsigned short*)bm);

    const dim3 gqkv(DD / 64, MM / 128, 3);        // 1536 blocks, one dispatch
    gemm_qkv<<<gqkv, 256, 0, stream>>>(qx, kx, vx, wqh, wkh, wvh,
                                       bq, bk, bv, Qh, Kh, Vt);

    const dim3 gattn(BB * HH, SS / 128);          // (32, 16): bh fastest
    attn_mfma4<<<gattn, 256, 0, stream>>>(Qh, Kh, Vt, bm, AO);

    const dim3 gout(DD / 64, MM / 128);
    gemm_out<<<gout, 256, 0, stream>>>(AO, woh, bo, out);
}